// Round 11
// baseline (2401.492 us; speedup 1.0000x reference)
//
#include <hip/hip_runtime.h>
#include <stdint.h>

namespace {

typedef unsigned long long ull;
constexpr int B = 4, C = 128, H = 256, W = 256;
constexpr int V = H * W;              // 65536
constexpr int E = 163072;             // 32640+32512+32640+32512+32768
constexpr long long CHW = (long long)C * V;
constexpr int ROUNDS = 17;
constexpr int NBLKV = (B * V) / 256;  // 1024 vertex blocks
constexpr int SEG = 768;              // <=3 owned edges per vertex * 256

// Edge enumeration matches reference concat order: [L-vert, L-horiz, R-vert, R-horiz, cross]
__device__ __forceinline__ void edge_uv(int e, int& u, int& v) {
  if (e < 32640) {                       // L vertical
    int h = e >> 7, w = e & 127;
    u = (h << 8) + w; v = u + 256;
  } else if (e < 65152) {                // L horizontal
    int k = e - 32640; int h = k / 127, w = k - h * 127;
    u = (h << 8) + w; v = u + 1;
  } else if (e < 97792) {                // R vertical
    int k = e - 65152; int h = k >> 7, w = k & 127;
    u = (h << 8) + 128 + w; v = u + 256;
  } else if (e < 130304) {               // R horizontal
    int k = e - 97792; int h = k / 127, w = k - h * 127;
    u = (h << 8) + 128 + w; v = u + 1;
  } else {                               // cross
    int k = e - 130304; int h = k >> 7, w = k & 127;
    u = (h << 8) + w; v = u + 128;
  }
}

// Chase to effective root: self-loop, or min-id member of a 2-cycle
// (== reference cyc-break). Verified exact R1-R10. Requires stable parent.
__device__ __forceinline__ int find_root(const int* __restrict__ par, int v) {
  int cur = v;
  int p = par[cur];
  for (int g = 0; g < 70000 && p != cur; ++g) {
    int gp = par[p];
    if (gp == cur) { cur = cur < p ? cur : p; break; }   // 2-cycle -> min id
    cur = p; p = gp;
  }
  return cur;
}

// Pass 1: per-pixel squared norm (fp64, verified fma chain).
__global__ void k_norm(const float* __restrict__ x, double* __restrict__ n2) {
  int idx = blockIdx.x * blockDim.x + threadIdx.x;   // exact B*V grid
  int b = idx >> 16, p = idx & (V - 1);
  const float* xb = x + (long long)b * CHW + p;
  double acc = 0.0;
#pragma unroll 8
  for (int c = 0; c < C; ++c) {
    double t = (double)xb[(long long)c * V];
    acc = fma(t, t, acc);
  }
  n2[idx] = acc;
}

// Pass 2: per-edge cosine (fp64 dot), verified bit-identical math. Zeroes out.
__global__ void k_weight(const float* __restrict__ x, const double* __restrict__ n2,
                         ull* __restrict__ wkey, float* __restrict__ out) {
  int idx = blockIdx.x * blockDim.x + threadIdx.x;   // exact B*E grid
  int b = idx / E, e = idx - b * E;
  int u, v; edge_uv(e, u, v);
  const float* xb = x + (long long)b * CHW;
  double dot = 0.0;
#pragma unroll 8
  for (int c = 0; c < C; ++c) {
    long long off = (long long)c * V;
    dot = fma((double)xb[off + u], (double)xb[off + v], dot);
  }
  double denom = fmax(sqrt(n2[(b << 16) + u]) * sqrt(n2[(b << 16) + v]), 1e-8);
  float w = (float)(dot / denom);
  unsigned int bits = __float_as_uint(w);
  if (w == 0.0f) bits = 0u;                          // collapse -0.0
  unsigned int mapped = bits ^ (((int)bits < 0) ? 0xFFFFFFFFu : 0x80000000u);
  wkey[idx] = ((ull)mapped << 32) | (unsigned int)e;
  out[idx] = 0.0f;
}

// Round 0 fused (vmin0+hook0): at r0 each vertex IS its component, so its
// min is purely local: min over <=5 incident edge keys. Mark + hook + init
// minE. No cross-thread dependencies at all. (R10-verified logic, fused.)
__global__ void k_r0(const ull* __restrict__ wkey, ull* __restrict__ minE,
                     int* __restrict__ parent, float* __restrict__ out) {
  int idx = blockIdx.x * blockDim.x + threadIdx.x;   // exact B*V grid
  int b = idx >> 16, v = idx & (V - 1);
  int h = v >> 8, w = v & 255;
  bool isL = w < 128;
  int wl = isL ? w : w - 128;
  int vb = isL ? 0 : 65152, hb = isL ? 32640 : 97792;
  const ull* wk = wkey + (size_t)b * E;
  ull m = ~0ULL;
  if (h > 0)    m = min(m, wk[vb + ((h - 1) << 7) + wl]);  // up
  if (h < 255)  m = min(m, wk[vb + (h << 7) + wl]);        // down
  if (wl > 0)   m = min(m, wk[hb + h * 127 + wl - 1]);     // left
  if (wl < 127) m = min(m, wk[hb + h * 127 + wl]);         // right
  m = min(m, wk[130304 + (h << 7) + wl]);                  // cross (both sides)
  int e = (int)(m & 0xFFFFFFFFu);
  int eu, ev; edge_uv(e, eu, ev);
  out[(size_t)b * E + e] = 1.0f;                     // winner (idempotent dup)
  parent[idx] = (v == eu) ? ev : eu;                 // hook to other endpoint
  minE[idx] = ~0ULL;                                 // arm for round 1
}

// Round 1 phase 1: per-vertex root snapshot (coalesced first hop).
__global__ void k_root(const int* __restrict__ parent, int* __restrict__ root) {
  int idx = blockIdx.x * blockDim.x + threadIdx.x;   // exact B*V grid
  int b = idx >> 16;
  root[idx] = find_root(parent + (b << 16), idx & (V - 1));
}

// Round 1 phase 2: per-vertex min over ALL 5 incident cross edges (one
// atomicMin), PLUS append owned still-cross edges (down/right/cross-if-L)
// into this block's private elseg segment. (R10-verified incl. cross fix.)
__global__ void k_vmin1(const int* __restrict__ root, const ull* __restrict__ wkey,
                        ull* __restrict__ minE,
                        int* __restrict__ elseg, int* __restrict__ cntblk) {
  __shared__ int lcnt;
  if (threadIdx.x == 0) lcnt = 0;
  __syncthreads();
  int idx = blockIdx.x * blockDim.x + threadIdx.x;   // exact B*V grid
  int b = idx >> 16, v = idx & (V - 1);
  int h = v >> 8, w = v & 255;
  bool isL = w < 128;
  int wl = isL ? w : w - 128;
  int vb = isL ? 0 : 65152, hb = isL ? 32640 : 97792;
  const int* rt = root + (b << 16);
  const ull* wk = wkey + (size_t)b * E;
  int rme = rt[v];
  ull m = ~0ULL;
  int base = blockIdx.x * SEG;
  // not owned: up / left / (cross for right half) -> min candidates only
  if (h > 0   && rt[v - 256] != rme) m = min(m, wk[vb + ((h - 1) << 7) + wl]);
  if (wl > 0  && rt[v - 1]   != rme) m = min(m, wk[hb + h * 127 + wl - 1]);
  if (!isL    && rt[v - 128] != rme) m = min(m, wk[130304 + (h << 7) + wl]);
  // owned: down / right / (cross for left half) -> min candidates + append
  if (h < 255 && rt[v + 256] != rme) {
    int e = vb + (h << 7) + wl;
    m = min(m, wk[e]);
    elseg[base + atomicAdd(&lcnt, 1)] = e;
  }
  if (wl < 127 && rt[v + 1] != rme) {
    int e = hb + h * 127 + wl;
    m = min(m, wk[e]);
    elseg[base + atomicAdd(&lcnt, 1)] = e;
  }
  if (isL && rt[v + 128] != rme) {
    int e = 130304 + (h << 7) + wl;
    m = min(m, wk[e]);
    elseg[base + atomicAdd(&lcnt, 1)] = e;
  }
  if (m != ~0ULL) atomicMin(minE + (b << 16) + rme, m);  // fire-and-forget
  __syncthreads();
  if (threadIdx.x == 0) cntblk[blockIdx.x] = lcnt;
}

// Round 1 phase 3: winners + hook + full path compression (snapshot root[]).
__global__ void k_hook1(ull* __restrict__ minE, const int* __restrict__ root,
                        int* __restrict__ parent, float* __restrict__ out) {
  int idx = blockIdx.x * blockDim.x + threadIdx.x;   // exact B*V grid
  int b = idx >> 16, v = idx & (V - 1);
  int rr = root[idx];
  int np = rr;                                       // compression (non-roots)
  if (rr == v) {
    ull k = minE[idx];
    if (k != ~0ULL) {
      int e = (int)(k & 0xFFFFFFFFu);
      int eu, ev; edge_uv(e, eu, ev);
      const int* rt = root + (b << 16);
      int ru = rt[eu], rv2 = rt[ev];
      out[(size_t)b * E + e] = 1.0f;                 // winner (idempotent dup)
      np = (v == ru) ? rv2 : ru;                     // hook to other component
      minE[idx] = ~0ULL;                             // re-arm dirtied slot
    }
  }
  int* par = parent + (b << 16);
  if (par[v] != np) par[v] = np;
}

// Rounds 2..16: ONE persistent workgroup per batch (batch-private state, no
// inter-workgroup traffic; intra-CU s_barrier instead of kernel launches).
// Per round: A) chase+atomicMin+in-place compact; B) winner-claim via
// low32(minE[root])==e (roots carried per edge, NO chases); C) re-arm.
// minE is RMW'd by L1-bypassing atomics in A, so B/C use agent-scope atomic
// load/store (plain loads could hit a stale L1 line within one kernel).
__global__ __launch_bounds__(1024)
void k_tail(int* __restrict__ parent, ull* __restrict__ minE,
            const ull* __restrict__ wkey, float* __restrict__ out,
            const int* __restrict__ elseg, const int* __restrict__ cntblk,
            int* __restrict__ fe, unsigned int* __restrict__ fr) {
  int b = blockIdx.x, t = threadIdx.x;
  const ull* wk = wkey + (size_t)b * E;
  ull* mb = minE + (b << 16);
  int* par = parent + (b << 16);
  float* ob = out + (size_t)b * E;
  int* feb = fe + (size_t)b * E;
  unsigned int* frb = fr + (size_t)b * E;

  __shared__ int pre[257];
  __shared__ int wofs[16];
  __shared__ int s_wc;

  // ---- phase 0: gather round-1 survivor segments into contiguous frontier
  if (t == 0) pre[0] = 0;
  if (t < 256) pre[t + 1] = cntblk[(b << 8) + t];
  __syncthreads();
  for (int ofs = 1; ofs < 256; ofs <<= 1) {          // inclusive scan pre[1..256]
    int cur = 0, add = 0;
    if (t < 256) {
      cur = pre[t + 1];
      if (t + 1 > ofs) add = pre[t + 1 - ofs];
    }
    __syncthreads();
    if (t < 256) pre[t + 1] = cur + add;
    __syncthreads();
  }
  if (t < 256) {
    int dst = pre[t], cnt = pre[t + 1] - dst;
    int src = ((b << 8) + t) * SEG;
    for (int i = 0; i < cnt; ++i) feb[dst + i] = elseg[src + i];
  }
  __syncthreads();
  int n = pre[256];

  for (int round = 2; round < ROUNDS && n > 0; ++round) {
    // ---- phase A: chase roots, atomicMin, compact survivors in place
    if (t == 0) s_wc = 0;
    __syncthreads();
    for (int base = 0; base < n; base += 1024) {
      int i = base + t;
      bool keep = false; int e = 0; unsigned int pr = 0;
      if (i < n) {
        e = feb[i];
        int u, v; edge_uv(e, u, v);
        int ru = find_root(par, u);
        int rv = find_root(par, v);
        if (ru != rv) {
          keep = true;
          pr = ((unsigned int)ru << 16) | (unsigned int)rv;
          ull k = wk[e];
          atomicMin(mb + ru, k);
          atomicMin(mb + rv, k);
        }
      }
      ull msk = __ballot(keep);
      int lane = t & 63, wid = t >> 6;
      if (lane == 0) wofs[wid] = (int)__popcll(msk);
      __syncthreads();
      if (t == 0) {
        int s = s_wc;
#pragma unroll
        for (int k2 = 0; k2 < 16; ++k2) { int c = wofs[k2]; wofs[k2] = s; s += c; }
        s_wc = s;
      }
      __syncthreads();
      if (keep) {
        int pos = wofs[wid] + (int)__popcll(msk & ((1ULL << lane) - 1));
        feb[pos] = e;                                // pos < base+1024 <= next reads
        frb[pos] = pr;
      }
    }
    __syncthreads();
    int kept = s_wc;
    // ---- phase B: winner-claim + mark + hook (no chases, snapshot roots)
    for (int i = t; i < kept; i += 1024) {
      unsigned int pr = frb[i];
      int ru = (int)(pr >> 16), rv = (int)(pr & 0xFFFFu);
      int e = feb[i];
      ull mu = __hip_atomic_load(mb + ru, __ATOMIC_RELAXED, __HIP_MEMORY_SCOPE_AGENT);
      ull mv = __hip_atomic_load(mb + rv, __ATOMIC_RELAXED, __HIP_MEMORY_SCOPE_AGENT);
      bool wu = ((int)(mu & 0xFFFFFFFFu) == e);
      bool wv = ((int)(mv & 0xFFFFFFFFu) == e);
      if (wu | wv) ob[e] = 1.0f;                     // this component's min edge
      if (wu) par[ru] = rv;                          // unique writer per root
      if (wv) par[rv] = ru;                          // mutual pair -> 2-cycle
    }
    __syncthreads();
    // ---- phase C: re-arm dirtied minE slots (idempotent dup writes)
    for (int i = t; i < kept; i += 1024) {
      unsigned int pr = frb[i];
      __hip_atomic_store(mb + (int)(pr >> 16), ~0ULL, __ATOMIC_RELAXED,
                         __HIP_MEMORY_SCOPE_AGENT);
      __hip_atomic_store(mb + (int)(pr & 0xFFFFu), ~0ULL, __ATOMIC_RELAXED,
                         __HIP_MEMORY_SCOPE_AGENT);
    }
    n = kept;
    __syncthreads();                                 // parent/minE ready for next A
  }
}

} // namespace

extern "C" void kernel_launch(void* const* d_in, const int* in_sizes, int n_in,
                              void* d_out, int out_size, void* d_ws, size_t ws_size,
                              hipStream_t stream) {
  const float* x = (const float*)d_in[0];
  float* out = (float*)d_out;

  char* ws = (char*)d_ws;
  size_t off = 0;
  auto alloc = [&](size_t bytes) {
    void* p = (void*)(ws + off);
    off += (bytes + 255) & ~(size_t)255;
    return p;
  };
  int* parent = (int*)alloc((size_t)B * V * sizeof(int));                      // 1 MB
  int* root   = (int*)alloc((size_t)B * V * sizeof(int));                      // 1 MB
  ull* minE   = (ull*)alloc((size_t)B * V * 8);                                // 2 MB
  double* n2  = (double*)alloc((size_t)B * V * sizeof(double));                // 2 MB
  ull* wkey   = (ull*)alloc((size_t)B * E * 8);                                // ~5.2 MB
  int* elseg  = (int*)alloc((size_t)NBLKV * SEG * sizeof(int));                // 3 MB
  int* cntblk = (int*)alloc((size_t)NBLKV * sizeof(int));
  int* fe     = (int*)alloc((size_t)B * E * sizeof(int));                      // ~2.6 MB
  unsigned int* fr = (unsigned int*)alloc((size_t)B * E * sizeof(int));        // ~2.6 MB

  k_norm  <<<(B * V) / 256, 256, 0, stream>>>(x, n2);
  k_weight<<<(B * E) / 256, 256, 0, stream>>>(x, n2, wkey, out);
  k_r0    <<<(B * V) / 256, 256, 0, stream>>>(wkey, minE, parent, out);

  k_root <<<NBLKV, 256, 0, stream>>>(parent, root);
  k_vmin1<<<NBLKV, 256, 0, stream>>>(root, wkey, minE, elseg, cntblk);
  k_hook1<<<NBLKV, 256, 0, stream>>>(minE, root, parent, out);

  k_tail<<<B, 1024, 0, stream>>>(parent, minE, wkey, out, elseg, cntblk, fe, fr);
}

// Round 12
// 306.293 us; speedup vs baseline: 7.8405x; 7.8405x over previous
//
#include <hip/hip_runtime.h>
#include <stdint.h>

namespace {

typedef unsigned long long ull;
constexpr int B = 4, C = 128, H = 256, W = 256;
constexpr int V = H * W;              // 65536
constexpr int E = 163072;             // 32640+32512+32640+32512+32768
constexpr long long CHW = (long long)C * V;
constexpr int ROUNDS = 17;
constexpr int NBLKV = (B * V) / 256;  // 1024 vertex blocks
constexpr int SEG = 768;              // <=3 owned edges per vertex * 256

// Edge enumeration matches reference concat order: [L-vert, L-horiz, R-vert, R-horiz, cross]
__device__ __forceinline__ void edge_uv(int e, int& u, int& v) {
  if (e < 32640) {                       // L vertical
    int h = e >> 7, w = e & 127;
    u = (h << 8) + w; v = u + 256;
  } else if (e < 65152) {                // L horizontal
    int k = e - 32640; int h = k / 127, w = k - h * 127;
    u = (h << 8) + w; v = u + 1;
  } else if (e < 97792) {                // R vertical
    int k = e - 65152; int h = k >> 7, w = k & 127;
    u = (h << 8) + 128 + w; v = u + 256;
  } else if (e < 130304) {               // R horizontal
    int k = e - 97792; int h = k / 127, w = k - h * 127;
    u = (h << 8) + 128 + w; v = u + 1;
  } else {                               // cross
    int k = e - 130304; int h = k >> 7, w = k & 127;
    u = (h << 8) + w; v = u + 128;
  }
}

// Chase to effective root: self-loop, or min-id member of a 2-cycle
// (== reference cyc-break). Verified exact R1-R11. Requires stable parent.
__device__ __forceinline__ int find_root(const int* __restrict__ par, int v) {
  int cur = v;
  int p = par[cur];
  for (int g = 0; g < 70000 && p != cur; ++g) {
    int gp = par[p];
    if (gp == cur) { cur = cur < p ? cur : p; break; }   // 2-cycle -> min id
    cur = p; p = gp;
  }
  return cur;
}

// Pass 1: per-pixel squared norm (fp64, verified fma chain) + flags init.
// flags[2]=1 (edge-mode round 3 always attempts), others 0.
__global__ void k_norm(const float* __restrict__ x, double* __restrict__ n2,
                       int* __restrict__ flags) {
  int idx = blockIdx.x * blockDim.x + threadIdx.x;   // exact B*V grid
  int b = idx >> 16, p = idx & (V - 1);
  const float* xb = x + (long long)b * CHW + p;
  double acc = 0.0;
#pragma unroll 8
  for (int c = 0; c < C; ++c) {
    double t = (double)xb[(long long)c * V];
    acc = fma(t, t, acc);
  }
  n2[idx] = acc;
  if (idx < 32) flags[idx] = (idx <= 2) ? 1 : 0;
}

// Pass 2: per-edge cosine (fp64 dot), verified bit-identical math. Zeroes out.
__global__ void k_weight(const float* __restrict__ x, const double* __restrict__ n2,
                         ull* __restrict__ wkey, float* __restrict__ out) {
  int idx = blockIdx.x * blockDim.x + threadIdx.x;   // exact B*E grid
  int b = idx / E, e = idx - b * E;
  int u, v; edge_uv(e, u, v);
  const float* xb = x + (long long)b * CHW;
  double dot = 0.0;
#pragma unroll 8
  for (int c = 0; c < C; ++c) {
    long long off = (long long)c * V;
    dot = fma((double)xb[off + u], (double)xb[off + v], dot);
  }
  double denom = fmax(sqrt(n2[(b << 16) + u]) * sqrt(n2[(b << 16) + v]), 1e-8);
  float w = (float)(dot / denom);
  unsigned int bits = __float_as_uint(w);
  if (w == 0.0f) bits = 0u;                          // collapse -0.0
  unsigned int mapped = bits ^ (((int)bits < 0) ? 0xFFFFFFFFu : 0x80000000u);
  wkey[idx] = ((ull)mapped << 32) | (unsigned int)e;
  out[idx] = 0.0f;
}

// Round 0 fused: each vertex IS its component; local min over <=5 incident
// keys; mark + hook + arm BOTH minE buffers. (R10/R11-verified logic.)
__global__ void k_r0(const ull* __restrict__ wkey, ull* __restrict__ minE0,
                     ull* __restrict__ minE1, int* __restrict__ parent,
                     float* __restrict__ out) {
  int idx = blockIdx.x * blockDim.x + threadIdx.x;   // exact B*V grid
  int b = idx >> 16, v = idx & (V - 1);
  int h = v >> 8, w = v & 255;
  bool isL = w < 128;
  int wl = isL ? w : w - 128;
  int vb = isL ? 0 : 65152, hb = isL ? 32640 : 97792;
  const ull* wk = wkey + (size_t)b * E;
  ull m = ~0ULL;
  if (h > 0)    m = min(m, wk[vb + ((h - 1) << 7) + wl]);  // up
  if (h < 255)  m = min(m, wk[vb + (h << 7) + wl]);        // down
  if (wl > 0)   m = min(m, wk[hb + h * 127 + wl - 1]);     // left
  if (wl < 127) m = min(m, wk[hb + h * 127 + wl]);         // right
  m = min(m, wk[130304 + (h << 7) + wl]);                  // cross (both sides)
  int e = (int)(m & 0xFFFFFFFFu);
  int eu, ev; edge_uv(e, eu, ev);
  out[(size_t)b * E + e] = 1.0f;                     // winner (idempotent dup)
  parent[idx] = (v == eu) ? ev : eu;                 // hook to other endpoint
  minE0[idx] = ~0ULL;                                // arm buffer 0
  minE1[idx] = ~0ULL;                                // arm buffer 1
}

// Per-vertex root snapshot (coalesced first hop). Used for rounds 1 and 2.
__global__ void k_root(const int* __restrict__ parent, int* __restrict__ root) {
  int idx = blockIdx.x * blockDim.x + threadIdx.x;   // exact B*V grid
  int b = idx >> 16;
  root[idx] = find_root(parent + (b << 16), idx & (V - 1));
}

// Round 1 vmin: per-vertex min over all 5 incident cross edges, one
// fire-and-forget atomicMin into own root. (R7/R10-verified, incl. the
// both-sides cross candidate.) No list output at r1.
__global__ void k_vminR1(const int* __restrict__ root, const ull* __restrict__ wkey,
                         ull* __restrict__ minE) {
  int idx = blockIdx.x * blockDim.x + threadIdx.x;   // exact B*V grid
  int b = idx >> 16, v = idx & (V - 1);
  int h = v >> 8, w = v & 255;
  bool isL = w < 128;
  int wl = isL ? w : w - 128;
  int vb = isL ? 0 : 65152, hb = isL ? 32640 : 97792;
  const int* rt = root + (b << 16);
  const ull* wk = wkey + (size_t)b * E;
  int rme = rt[v];
  ull m = ~0ULL;
  if (h > 0    && rt[v - 256] != rme) m = min(m, wk[vb + ((h - 1) << 7) + wl]);
  if (h < 255  && rt[v + 256] != rme) m = min(m, wk[vb + (h << 7) + wl]);
  if (wl > 0   && rt[v - 1]   != rme) m = min(m, wk[hb + h * 127 + wl - 1]);
  if (wl < 127 && rt[v + 1]   != rme) m = min(m, wk[hb + h * 127 + wl]);
  int xn = isL ? v + 128 : v - 128;
  if (rt[xn] != rme) m = min(m, wk[130304 + (h << 7) + wl]);
  if (m != ~0ULL) atomicMin(minE + (b << 16) + rme, m);  // fire-and-forget
}

// Round 2 vmin: same min logic PLUS append owned still-cross edges
// (down/right/cross-if-L) into this block's private segment -> seeds the
// round-3 edge frontier. (R10-verified vmin1 code, run at r2.)
__global__ void k_vminR2(const int* __restrict__ root, const ull* __restrict__ wkey,
                         ull* __restrict__ minE,
                         int* __restrict__ elseg, int* __restrict__ cntblk) {
  __shared__ int lcnt;
  if (threadIdx.x == 0) lcnt = 0;
  __syncthreads();
  int idx = blockIdx.x * blockDim.x + threadIdx.x;   // exact B*V grid
  int b = idx >> 16, v = idx & (V - 1);
  int h = v >> 8, w = v & 255;
  bool isL = w < 128;
  int wl = isL ? w : w - 128;
  int vb = isL ? 0 : 65152, hb = isL ? 32640 : 97792;
  const int* rt = root + (b << 16);
  const ull* wk = wkey + (size_t)b * E;
  int rme = rt[v];
  ull m = ~0ULL;
  int base = blockIdx.x * SEG;
  // not owned: up / left / (cross for right half) -> min candidates only
  if (h > 0   && rt[v - 256] != rme) m = min(m, wk[vb + ((h - 1) << 7) + wl]);
  if (wl > 0  && rt[v - 1]   != rme) m = min(m, wk[hb + h * 127 + wl - 1]);
  if (!isL    && rt[v - 128] != rme) m = min(m, wk[130304 + (h << 7) + wl]);
  // owned: down / right / (cross for left half) -> min candidates + append
  if (h < 255 && rt[v + 256] != rme) {
    int e = vb + (h << 7) + wl;
    m = min(m, wk[e]);
    elseg[base + atomicAdd(&lcnt, 1)] = e;
  }
  if (wl < 127 && rt[v + 1] != rme) {
    int e = hb + h * 127 + wl;
    m = min(m, wk[e]);
    elseg[base + atomicAdd(&lcnt, 1)] = e;
  }
  if (isL && rt[v + 128] != rme) {
    int e = 130304 + (h << 7) + wl;
    m = min(m, wk[e]);
    elseg[base + atomicAdd(&lcnt, 1)] = e;
  }
  if (m != ~0ULL) atomicMin(minE + (b << 16) + rme, m);  // fire-and-forget
  __syncthreads();
  if (threadIdx.x == 0) cntblk[blockIdx.x] = lcnt;
}

// Rounds 1-2 hook: winners + hook + FULL path compression (snapshot root[]),
// re-arm dirtied minE slots. (R10-verified.)
__global__ void k_hookV(ull* __restrict__ minE, const int* __restrict__ root,
                        int* __restrict__ parent, float* __restrict__ out) {
  int idx = blockIdx.x * blockDim.x + threadIdx.x;   // exact B*V grid
  int b = idx >> 16, v = idx & (V - 1);
  int rr = root[idx];
  int np = rr;                                       // compression (non-roots)
  if (rr == v) {
    ull k = minE[idx];
    if (k != ~0ULL) {
      int e = (int)(k & 0xFFFFFFFFu);
      int eu, ev; edge_uv(e, eu, ev);
      const int* rt = root + (b << 16);
      int ru = rt[eu], rv2 = rt[ev];
      out[(size_t)b * E + e] = 1.0f;                 // winner (idempotent dup)
      np = (v == ru) ? rv2 : ru;                     // hook to other component
      minE[idx] = ~0ULL;                             // re-arm dirtied slot
    }
  }
  int* par = parent + (b << 16);
  if (par[v] != np) par[v] = np;
}

// Rounds 3..16 phase A: per-block segment; chase both roots on stable parent,
// atomicMin into CURRENT minE buffer, in-place compact survivors + their
// root pairs. (R10-verified k_edge structure + R11-verified pair carry.)
__global__ void k_edgeA(const int* __restrict__ parent, const ull* __restrict__ wkey,
                        ull* __restrict__ mcur, int* __restrict__ elseg,
                        unsigned int* __restrict__ prblk, int* __restrict__ cntblk,
                        int* __restrict__ flags, int r) {
  if (__hip_atomic_load(flags + r - 1, __ATOMIC_RELAXED,
                        __HIP_MEMORY_SCOPE_AGENT) == 0)
    return;                                          // converged
  int j = blockIdx.x, t = threadIdx.x;
  int n = cntblk[j];
  if (n == 0) return;                                // uniform per block
  __shared__ int lcnt;
  if (t == 0) lcnt = 0;
  int b = j >> 8;                                    // 256 vertex-blocks/batch
  const int* par = parent + (b << 16);
  const ull* wk = wkey + (size_t)b * E;
  ull* mb = mcur + (b << 16);
  int base = j * SEG;
  int se[3]; unsigned int sp[3]; int ns = 0;
#pragma unroll
  for (int it = 0; it < 3; ++it) {                   // reads BEFORE barrier
    int i = t + (it << 8);
    if (i < n) {
      int e = elseg[base + i];
      int u, v; edge_uv(e, u, v);
      int ru = find_root(par, u);
      int rv = find_root(par, v);
      if (ru != rv) {
        ull k = wk[e];
        atomicMin(mb + ru, k);                       // fire-and-forget
        atomicMin(mb + rv, k);
        se[ns] = e;
        sp[ns] = ((unsigned int)ru << 16) | (unsigned int)rv;
        ++ns;
      }
    }
  }
  __syncthreads();                                   // all reads done
  for (int i2 = 0; i2 < ns; ++i2) {
    int pos = atomicAdd(&lcnt, 1);                   // LDS, block-local
    elseg[base + pos] = se[i2];
    prblk[base + pos] = sp[i2];
  }
  __syncthreads();
  if (t == 0) {
    cntblk[j] = lcnt;
    if (lcnt &&
        __hip_atomic_load(flags + r, __ATOMIC_RELAXED, __HIP_MEMORY_SCOPE_AGENT) == 0)
      __hip_atomic_fetch_or(flags + r, 1, __ATOMIC_RELAXED, __HIP_MEMORY_SCOPE_AGENT);
  }
}

// Rounds 3..16 phase B: winner-claim WITHOUT chases (carried pairs +
// low32(minE[root])==e, R11-verified), mark out, hook parent (unique writer
// per root; mutual pairs -> 2-cycles handled by find_root), and ARM the
// NEXT minE buffer at both pair roots. Arming covers every future dirty
// slot: any root merging in a later round appears as a pair-root of a kept
// edge this round (its min edge is kept; frontier only shrinks).
__global__ void k_edgeB(const ull* __restrict__ mcur, ull* __restrict__ mnext,
                        const int* __restrict__ elseg,
                        const unsigned int* __restrict__ prblk,
                        const int* __restrict__ cntblk,
                        int* __restrict__ parent, float* __restrict__ out,
                        const int* __restrict__ flags, int r) {
  if (__hip_atomic_load(flags + r, __ATOMIC_RELAXED,
                        __HIP_MEMORY_SCOPE_AGENT) == 0)
    return;                                          // nothing kept this round
  int j = blockIdx.x, t = threadIdx.x;
  int n = cntblk[j];
  if (n == 0) return;
  int b = j >> 8;
  const ull* mbc = mcur + (b << 16);
  ull* mbn = mnext + (b << 16);
  int* par = parent + (b << 16);
  float* ob = out + (size_t)b * E;
  int base = j * SEG;
  for (int i = t; i < n; i += 256) {
    int e = elseg[base + i];
    unsigned int pr = prblk[base + i];
    int ru = (int)(pr >> 16), rv = (int)(pr & 0xFFFFu);
    ull mu = mbc[ru];                                // cross-dispatch: fresh
    ull mv = mbc[rv];
    bool wu = ((int)(mu & 0xFFFFFFFFu) == e);
    bool wv = ((int)(mv & 0xFFFFFFFFu) == e);
    if (wu | wv) ob[e] = 1.0f;                       // component min edge
    if (wu) par[ru] = rv;                            // unique writer per root
    if (wv) par[rv] = ru;                            // mutual -> 2-cycle
    mbn[ru] = ~0ULL;                                 // arm next buffer
    mbn[rv] = ~0ULL;                                 // (idempotent dups)
  }
}

} // namespace

extern "C" void kernel_launch(void* const* d_in, const int* in_sizes, int n_in,
                              void* d_out, int out_size, void* d_ws, size_t ws_size,
                              hipStream_t stream) {
  const float* x = (const float*)d_in[0];
  float* out = (float*)d_out;

  char* ws = (char*)d_ws;
  size_t off = 0;
  auto alloc = [&](size_t bytes) {
    void* p = (void*)(ws + off);
    off += (bytes + 255) & ~(size_t)255;
    return p;
  };
  int* parent = (int*)alloc((size_t)B * V * sizeof(int));                      // 1 MB
  int* root   = (int*)alloc((size_t)B * V * sizeof(int));                      // 1 MB
  ull* minE0  = (ull*)alloc((size_t)B * V * 8);                                // 2 MB
  ull* minE1  = (ull*)alloc((size_t)B * V * 8);                                // 2 MB
  double* n2  = (double*)alloc((size_t)B * V * sizeof(double));                // 2 MB
  ull* wkey   = (ull*)alloc((size_t)B * E * 8);                                // ~5.2 MB
  int* elseg  = (int*)alloc((size_t)NBLKV * SEG * sizeof(int));                // 3 MB
  unsigned int* prblk = (unsigned int*)alloc((size_t)NBLKV * SEG * 4);         // 3 MB
  int* cntblk = (int*)alloc((size_t)NBLKV * sizeof(int));
  int* flags  = (int*)alloc(32 * sizeof(int));

  k_norm  <<<(B * V) / 256, 256, 0, stream>>>(x, n2, flags);
  k_weight<<<(B * E) / 256, 256, 0, stream>>>(x, n2, wkey, out);
  k_r0    <<<(B * V) / 256, 256, 0, stream>>>(wkey, minE0, minE1, parent, out);

  // round 1 (per-vertex, minE0)
  k_root  <<<NBLKV, 256, 0, stream>>>(parent, root);
  k_vminR1<<<NBLKV, 256, 0, stream>>>(root, wkey, minE0);
  k_hookV <<<NBLKV, 256, 0, stream>>>(minE0, root, parent, out);

  // round 2 (per-vertex, minE0; seeds round-3 edge frontier)
  k_root  <<<NBLKV, 256, 0, stream>>>(parent, root);
  k_vminR2<<<NBLKV, 256, 0, stream>>>(root, wkey, minE0, elseg, cntblk);
  k_hookV <<<NBLKV, 256, 0, stream>>>(minE0, root, parent, out);

  // rounds 3..16 (edge frontier, double-buffered minE)
  for (int r = 3; r < ROUNDS; ++r) {
    ull* mcur  = (r & 1) ? minE0 : minE1;            // r3 -> minE0 (armed)
    ull* mnext = (r & 1) ? minE1 : minE0;
    k_edgeA<<<NBLKV, 256, 0, stream>>>(parent, wkey, mcur, elseg, prblk,
                                       cntblk, flags, r);
    k_edgeB<<<NBLKV, 256, 0, stream>>>(mcur, mnext, elseg, prblk, cntblk,
                                       parent, out, flags, r);
  }
}

// Round 13
// 273.411 us; speedup vs baseline: 8.7834x; 1.1203x over previous
//
#include <hip/hip_runtime.h>
#include <stdint.h>

namespace {

typedef unsigned long long ull;
constexpr int B = 4, C = 128, H = 256, W = 256;
constexpr int V = H * W;              // 65536
constexpr int E = 163072;             // 32640+32512+32640+32512+32768
constexpr long long CHW = (long long)C * V;
constexpr int ROUNDS = 17;
constexpr int NBLKV = (B * V) / 256;  // 1024 vertex blocks
constexpr int SEG = 768;              // <=3 owned edges per vertex * 256

// Edge enumeration matches reference concat order: [L-vert, L-horiz, R-vert, R-horiz, cross]
__device__ __forceinline__ void edge_uv(int e, int& u, int& v) {
  if (e < 32640) {                       // L vertical
    int h = e >> 7, w = e & 127;
    u = (h << 8) + w; v = u + 256;
  } else if (e < 65152) {                // L horizontal
    int k = e - 32640; int h = k / 127, w = k - h * 127;
    u = (h << 8) + w; v = u + 1;
  } else if (e < 97792) {                // R vertical
    int k = e - 65152; int h = k >> 7, w = k & 127;
    u = (h << 8) + 128 + w; v = u + 256;
  } else if (e < 130304) {               // R horizontal
    int k = e - 97792; int h = k / 127, w = k - h * 127;
    u = (h << 8) + 128 + w; v = u + 1;
  } else {                               // cross
    int k = e - 130304; int h = k >> 7, w = k & 127;
    u = (h << 8) + w; v = u + 128;
  }
}

// Chase to effective root: self-loop, or min-id member of a 2-cycle
// (== reference cyc-break). Verified exact R1-R12. Requires stable parent.
__device__ __forceinline__ int find_root(const int* __restrict__ par, int v) {
  int cur = v;
  int p = par[cur];
  for (int g = 0; g < 70000 && p != cur; ++g) {
    int gp = par[p];
    if (gp == cur) { cur = cur < p ? cur : p; break; }   // 2-cycle -> min id
    cur = p; p = gp;
  }
  return cur;
}

// Fused head: pixel-PAIR threads, float2 loads, wave-uniform L/R split,
// BRANCH-FREE c-loop (clamped offsets hoisted). Accumulates the 6 owned
// dots (bit-identical chains to R6-verified k_weight2) AND the 7 norms the
// emits need (each norm = that pixel's own ascending-c fma chain, identical
// to the old k_norm). Emits wkeys + zeroes out slots. No atomics.
__global__ void k_weight3(const float* __restrict__ x, ull* __restrict__ wkey,
                          float* __restrict__ out) {
  int idx = blockIdx.x * blockDim.x + threadIdx.x;   // exact B*H*128 grid
  int b = idx >> 15, rem = idx & 32767;
  int h = rem >> 7, q = rem & 127;
  int w0 = q << 1;
  bool isL  = q < 64;                                // wave-uniform
  bool hasV = h < 255;
  int voff = hasV ? 256 : 0;                         // clamped when absent
  int roff = (isL ? (q < 63) : (q < 127)) ? 2 : 0;   // clamped when absent

  const float* xb = x + (long long)b * CHW + (h << 8) + w0;
  double n0x = 0, n0y = 0, ndnx = 0, ndny = 0, nrtx = 0, ncrx = 0, ncry = 0;
  double dv0 = 0, dv1 = 0, dh0 = 0, dh1 = 0, dx0 = 0, dx1 = 0;
  if (isL) {
#pragma unroll 4
    for (int c = 0; c < C; ++c) {
      const float* pc = xb + (long long)c * V;
      float2 a  = *(const float2*)pc;
      float2 dn = *(const float2*)(pc + voff);
      float2 rt = *(const float2*)(pc + roff);
      float2 cr = *(const float2*)(pc + 128);
      double ax = a.x, ay = a.y, dnx = dn.x, dny = dn.y, rtx = rt.x,
             crx = cr.x, cry = cr.y;
      n0x = fma(ax, ax, n0x);   n0y = fma(ay, ay, n0y);
      ndnx = fma(dnx, dnx, ndnx); ndny = fma(dny, dny, ndny);
      nrtx = fma(rtx, rtx, nrtx);
      ncrx = fma(crx, crx, ncrx); ncry = fma(cry, cry, ncry);
      dv0 = fma(ax, dnx, dv0);  dv1 = fma(ay, dny, dv1);
      dh0 = fma(ax, ay, dh0);   dh1 = fma(ay, rtx, dh1);
      dx0 = fma(ax, crx, dx0);  dx1 = fma(ay, cry, dx1);
    }
  } else {
#pragma unroll 4
    for (int c = 0; c < C; ++c) {
      const float* pc = xb + (long long)c * V;
      float2 a  = *(const float2*)pc;
      float2 dn = *(const float2*)(pc + voff);
      float2 rt = *(const float2*)(pc + roff);
      double ax = a.x, ay = a.y, dnx = dn.x, dny = dn.y, rtx = rt.x;
      n0x = fma(ax, ax, n0x);   n0y = fma(ay, ay, n0y);
      ndnx = fma(dnx, dnx, ndnx); ndny = fma(dny, dny, ndny);
      nrtx = fma(rtx, rtx, nrtx);
      dv0 = fma(ax, dnx, dv0);  dv1 = fma(ay, dny, dv1);
      dh0 = fma(ax, ay, dh0);   dh1 = fma(ay, rtx, dh1);
    }
  }

  ull* wk = wkey + (size_t)b * E;
  float* ob = out + (size_t)b * E;
  auto emit = [&](int e, double nu, double nv, double dot) {
    double denom = fmax(sqrt(nu) * sqrt(nv), 1e-8);
    float wv = (float)(dot / denom);
    unsigned int bits = __float_as_uint(wv);
    if (wv == 0.0f) bits = 0u;                       // collapse -0.0
    unsigned int mapped = bits ^ (((int)bits < 0) ? 0xFFFFFFFFu : 0x80000000u);
    wk[e] = ((ull)mapped << 32) | (unsigned int)e;
    ob[e] = 0.0f;
  };
  if (isL) {
    if (hasV) {
      emit((h << 7) + w0,     n0x, ndnx, dv0);
      emit((h << 7) + w0 + 1, n0y, ndny, dv1);
    }
    emit(32640 + h * 127 + w0, n0x, n0y, dh0);
    if (q < 63) emit(32640 + h * 127 + w0 + 1, n0y, nrtx, dh1);
    emit(130304 + (h << 7) + w0,     n0x, ncrx, dx0);
    emit(130304 + (h << 7) + w0 + 1, n0y, ncry, dx1);
  } else {
    int wr = w0 - 128;
    if (hasV) {
      emit(65152 + (h << 7) + wr,     n0x, ndnx, dv0);
      emit(65152 + (h << 7) + wr + 1, n0y, ndny, dv1);
    }
    emit(97792 + h * 127 + wr, n0x, n0y, dh0);
    if (q < 127) emit(97792 + h * 127 + wr + 1, n0y, nrtx, dh1);
  }
}

// Round 0 fused: each vertex IS its component; local min over <=5 incident
// keys; mark + hook + arm BOTH minE buffers + flags init. (R12-verified.)
__global__ void k_r0(const ull* __restrict__ wkey, ull* __restrict__ minE0,
                     ull* __restrict__ minE1, int* __restrict__ parent,
                     float* __restrict__ out, int* __restrict__ flags) {
  int idx = blockIdx.x * blockDim.x + threadIdx.x;   // exact B*V grid
  int b = idx >> 16, v = idx & (V - 1);
  int h = v >> 8, w = v & 255;
  bool isL = w < 128;
  int wl = isL ? w : w - 128;
  int vb = isL ? 0 : 65152, hb = isL ? 32640 : 97792;
  const ull* wk = wkey + (size_t)b * E;
  ull m = ~0ULL;
  if (h > 0)    m = min(m, wk[vb + ((h - 1) << 7) + wl]);  // up
  if (h < 255)  m = min(m, wk[vb + (h << 7) + wl]);        // down
  if (wl > 0)   m = min(m, wk[hb + h * 127 + wl - 1]);     // left
  if (wl < 127) m = min(m, wk[hb + h * 127 + wl]);         // right
  m = min(m, wk[130304 + (h << 7) + wl]);                  // cross (both sides)
  int e = (int)(m & 0xFFFFFFFFu);
  int eu, ev; edge_uv(e, eu, ev);
  out[(size_t)b * E + e] = 1.0f;                     // winner (idempotent dup)
  parent[idx] = (v == eu) ? ev : eu;                 // hook to other endpoint
  minE0[idx] = ~0ULL;                                // arm buffer 0
  minE1[idx] = ~0ULL;                                // arm buffer 1
  if (idx < 32) flags[idx] = (idx <= 2) ? 1 : 0;
}

// Per-vertex root snapshot (coalesced first hop). Used for rounds 1 and 2.
__global__ void k_root(const int* __restrict__ parent, int* __restrict__ root) {
  int idx = blockIdx.x * blockDim.x + threadIdx.x;   // exact B*V grid
  int b = idx >> 16;
  root[idx] = find_root(parent + (b << 16), idx & (V - 1));
}

// Round 1 vmin: per-vertex min over all 5 incident cross edges, one
// fire-and-forget atomicMin into own root. (R12-verified.)
__global__ void k_vminR1(const int* __restrict__ root, const ull* __restrict__ wkey,
                         ull* __restrict__ minE) {
  int idx = blockIdx.x * blockDim.x + threadIdx.x;   // exact B*V grid
  int b = idx >> 16, v = idx & (V - 1);
  int h = v >> 8, w = v & 255;
  bool isL = w < 128;
  int wl = isL ? w : w - 128;
  int vb = isL ? 0 : 65152, hb = isL ? 32640 : 97792;
  const int* rt = root + (b << 16);
  const ull* wk = wkey + (size_t)b * E;
  int rme = rt[v];
  ull m = ~0ULL;
  if (h > 0    && rt[v - 256] != rme) m = min(m, wk[vb + ((h - 1) << 7) + wl]);
  if (h < 255  && rt[v + 256] != rme) m = min(m, wk[vb + (h << 7) + wl]);
  if (wl > 0   && rt[v - 1]   != rme) m = min(m, wk[hb + h * 127 + wl - 1]);
  if (wl < 127 && rt[v + 1]   != rme) m = min(m, wk[hb + h * 127 + wl]);
  int xn = isL ? v + 128 : v - 128;
  if (rt[xn] != rme) m = min(m, wk[130304 + (h << 7) + wl]);
  if (m != ~0ULL) atomicMin(minE + (b << 16) + rme, m);  // fire-and-forget
}

// Round 2 vmin: same min logic PLUS append owned still-cross edges into this
// block's private segment -> seeds the round-3 edge frontier. (R12-verified.)
__global__ void k_vminR2(const int* __restrict__ root, const ull* __restrict__ wkey,
                         ull* __restrict__ minE,
                         int* __restrict__ elseg, int* __restrict__ cntblk) {
  __shared__ int lcnt;
  if (threadIdx.x == 0) lcnt = 0;
  __syncthreads();
  int idx = blockIdx.x * blockDim.x + threadIdx.x;   // exact B*V grid
  int b = idx >> 16, v = idx & (V - 1);
  int h = v >> 8, w = v & 255;
  bool isL = w < 128;
  int wl = isL ? w : w - 128;
  int vb = isL ? 0 : 65152, hb = isL ? 32640 : 97792;
  const int* rt = root + (b << 16);
  const ull* wk = wkey + (size_t)b * E;
  int rme = rt[v];
  ull m = ~0ULL;
  int base = blockIdx.x * SEG;
  // not owned: up / left / (cross for right half) -> min candidates only
  if (h > 0   && rt[v - 256] != rme) m = min(m, wk[vb + ((h - 1) << 7) + wl]);
  if (wl > 0  && rt[v - 1]   != rme) m = min(m, wk[hb + h * 127 + wl - 1]);
  if (!isL    && rt[v - 128] != rme) m = min(m, wk[130304 + (h << 7) + wl]);
  // owned: down / right / (cross for left half) -> min candidates + append
  if (h < 255 && rt[v + 256] != rme) {
    int e = vb + (h << 7) + wl;
    m = min(m, wk[e]);
    elseg[base + atomicAdd(&lcnt, 1)] = e;
  }
  if (wl < 127 && rt[v + 1] != rme) {
    int e = hb + h * 127 + wl;
    m = min(m, wk[e]);
    elseg[base + atomicAdd(&lcnt, 1)] = e;
  }
  if (isL && rt[v + 128] != rme) {
    int e = 130304 + (h << 7) + wl;
    m = min(m, wk[e]);
    elseg[base + atomicAdd(&lcnt, 1)] = e;
  }
  if (m != ~0ULL) atomicMin(minE + (b << 16) + rme, m);  // fire-and-forget
  __syncthreads();
  if (threadIdx.x == 0) cntblk[blockIdx.x] = lcnt;
}

// Rounds 1-2 hook: winners + hook + FULL path compression (snapshot root[]),
// re-arm dirtied minE slots. (R12-verified.)
__global__ void k_hookV(ull* __restrict__ minE, const int* __restrict__ root,
                        int* __restrict__ parent, float* __restrict__ out) {
  int idx = blockIdx.x * blockDim.x + threadIdx.x;   // exact B*V grid
  int b = idx >> 16, v = idx & (V - 1);
  int rr = root[idx];
  int np = rr;                                       // compression (non-roots)
  if (rr == v) {
    ull k = minE[idx];
    if (k != ~0ULL) {
      int e = (int)(k & 0xFFFFFFFFu);
      int eu, ev; edge_uv(e, eu, ev);
      const int* rt = root + (b << 16);
      int ru = rt[eu], rv2 = rt[ev];
      out[(size_t)b * E + e] = 1.0f;                 // winner (idempotent dup)
      np = (v == ru) ? rv2 : ru;                     // hook to other component
      minE[idx] = ~0ULL;                             // re-arm dirtied slot
    }
  }
  int* par = parent + (b << 16);
  if (par[v] != np) par[v] = np;
}

// Rounds 3..16 phase A: per-block segment; chase both roots on stable parent,
// atomicMin into CURRENT minE buffer, in-place compact survivors + their
// root pairs. (R12-verified.)
__global__ void k_edgeA(const int* __restrict__ parent, const ull* __restrict__ wkey,
                        ull* __restrict__ mcur, int* __restrict__ elseg,
                        unsigned int* __restrict__ prblk, int* __restrict__ cntblk,
                        int* __restrict__ flags, int r) {
  if (__hip_atomic_load(flags + r - 1, __ATOMIC_RELAXED,
                        __HIP_MEMORY_SCOPE_AGENT) == 0)
    return;                                          // converged
  int j = blockIdx.x, t = threadIdx.x;
  int n = cntblk[j];
  if (n == 0) return;                                // uniform per block
  __shared__ int lcnt;
  if (t == 0) lcnt = 0;
  int b = j >> 8;                                    // 256 vertex-blocks/batch
  const int* par = parent + (b << 16);
  const ull* wk = wkey + (size_t)b * E;
  ull* mb = mcur + (b << 16);
  int base = j * SEG;
  int se[3]; unsigned int sp[3]; int ns = 0;
#pragma unroll
  for (int it = 0; it < 3; ++it) {                   // reads BEFORE barrier
    int i = t + (it << 8);
    if (i < n) {
      int e = elseg[base + i];
      int u, v; edge_uv(e, u, v);
      int ru = find_root(par, u);
      int rv = find_root(par, v);
      if (ru != rv) {
        ull k = wk[e];
        atomicMin(mb + ru, k);                       // fire-and-forget
        atomicMin(mb + rv, k);
        se[ns] = e;
        sp[ns] = ((unsigned int)ru << 16) | (unsigned int)rv;
        ++ns;
      }
    }
  }
  __syncthreads();                                   // all reads done
  for (int i2 = 0; i2 < ns; ++i2) {
    int pos = atomicAdd(&lcnt, 1);                   // LDS, block-local
    elseg[base + pos] = se[i2];
    prblk[base + pos] = sp[i2];
  }
  __syncthreads();
  if (t == 0) {
    cntblk[j] = lcnt;
    if (lcnt &&
        __hip_atomic_load(flags + r, __ATOMIC_RELAXED, __HIP_MEMORY_SCOPE_AGENT) == 0)
      __hip_atomic_fetch_or(flags + r, 1, __ATOMIC_RELAXED, __HIP_MEMORY_SCOPE_AGENT);
  }
}

// Rounds 3..16 phase B: winner-claim without chases (carried pairs +
// low32(minE[root])==e), mark out, hook parent, arm NEXT minE buffer.
// (R12-verified, incl. the arming-coverage argument.)
__global__ void k_edgeB(const ull* __restrict__ mcur, ull* __restrict__ mnext,
                        const int* __restrict__ elseg,
                        const unsigned int* __restrict__ prblk,
                        const int* __restrict__ cntblk,
                        int* __restrict__ parent, float* __restrict__ out,
                        const int* __restrict__ flags, int r) {
  if (__hip_atomic_load(flags + r, __ATOMIC_RELAXED,
                        __HIP_MEMORY_SCOPE_AGENT) == 0)
    return;                                          // nothing kept this round
  int j = blockIdx.x, t = threadIdx.x;
  int n = cntblk[j];
  if (n == 0) return;
  int b = j >> 8;
  const ull* mbc = mcur + (b << 16);
  ull* mbn = mnext + (b << 16);
  int* par = parent + (b << 16);
  float* ob = out + (size_t)b * E;
  int base = j * SEG;
  for (int i = t; i < n; i += 256) {
    int e = elseg[base + i];
    unsigned int pr = prblk[base + i];
    int ru = (int)(pr >> 16), rv = (int)(pr & 0xFFFFu);
    ull mu = mbc[ru];                                // cross-dispatch: fresh
    ull mv = mbc[rv];
    bool wu = ((int)(mu & 0xFFFFFFFFu) == e);
    bool wv = ((int)(mv & 0xFFFFFFFFu) == e);
    if (wu | wv) ob[e] = 1.0f;                       // component min edge
    if (wu) par[ru] = rv;                            // unique writer per root
    if (wv) par[rv] = ru;                            // mutual -> 2-cycle
    mbn[ru] = ~0ULL;                                 // arm next buffer
    mbn[rv] = ~0ULL;                                 // (idempotent dups)
  }
}

} // namespace

extern "C" void kernel_launch(void* const* d_in, const int* in_sizes, int n_in,
                              void* d_out, int out_size, void* d_ws, size_t ws_size,
                              hipStream_t stream) {
  const float* x = (const float*)d_in[0];
  float* out = (float*)d_out;

  char* ws = (char*)d_ws;
  size_t off = 0;
  auto alloc = [&](size_t bytes) {
    void* p = (void*)(ws + off);
    off += (bytes + 255) & ~(size_t)255;
    return p;
  };
  int* parent = (int*)alloc((size_t)B * V * sizeof(int));                      // 1 MB
  int* root   = (int*)alloc((size_t)B * V * sizeof(int));                      // 1 MB
  ull* minE0  = (ull*)alloc((size_t)B * V * 8);                                // 2 MB
  ull* minE1  = (ull*)alloc((size_t)B * V * 8);                                // 2 MB
  ull* wkey   = (ull*)alloc((size_t)B * E * 8);                                // ~5.2 MB
  int* elseg  = (int*)alloc((size_t)NBLKV * SEG * sizeof(int));                // 3 MB
  unsigned int* prblk = (unsigned int*)alloc((size_t)NBLKV * SEG * 4);         // 3 MB
  int* cntblk = (int*)alloc((size_t)NBLKV * sizeof(int));
  int* flags  = (int*)alloc(32 * sizeof(int));

  k_weight3<<<(B * H * 128) / 256, 256, 0, stream>>>(x, wkey, out);
  k_r0     <<<(B * V) / 256, 256, 0, stream>>>(wkey, minE0, minE1, parent, out, flags);

  // round 1 (per-vertex, minE0)
  k_root  <<<NBLKV, 256, 0, stream>>>(parent, root);
  k_vminR1<<<NBLKV, 256, 0, stream>>>(root, wkey, minE0);
  k_hookV <<<NBLKV, 256, 0, stream>>>(minE0, root, parent, out);

  // round 2 (per-vertex, minE0; seeds round-3 edge frontier)
  k_root  <<<NBLKV, 256, 0, stream>>>(parent, root);
  k_vminR2<<<NBLKV, 256, 0, stream>>>(root, wkey, minE0, elseg, cntblk);
  k_hookV <<<NBLKV, 256, 0, stream>>>(minE0, root, parent, out);

  // rounds 3..16 (edge frontier, double-buffered minE)
  for (int r = 3; r < ROUNDS; ++r) {
    ull* mcur  = (r & 1) ? minE0 : minE1;            // r3 -> minE0 (armed)
    ull* mnext = (r & 1) ? minE1 : minE0;
    k_edgeA<<<NBLKV, 256, 0, stream>>>(parent, wkey, mcur, elseg, prblk,
                                       cntblk, flags, r);
    k_edgeB<<<NBLKV, 256, 0, stream>>>(mcur, mnext, elseg, prblk, cntblk,
                                       parent, out, flags, r);
  }
}

// Round 14
// 266.053 us; speedup vs baseline: 9.0264x; 1.0277x over previous
//
#include <hip/hip_runtime.h>
#include <stdint.h>

namespace {

typedef unsigned long long ull;
constexpr int B = 4, C = 128, H = 256, W = 256;
constexpr int V = H * W;              // 65536
constexpr int E = 163072;             // 32640+32512+32640+32512+32768
constexpr long long CHW = (long long)C * V;
constexpr int ROUNDS = 17;
constexpr int NBLKV = (B * V) / 256;  // 1024 vertex blocks
constexpr int SEG = 768;              // <=3 owned edges per vertex * 256

// Edge enumeration matches reference concat order: [L-vert, L-horiz, R-vert, R-horiz, cross]
__device__ __forceinline__ void edge_uv(int e, int& u, int& v) {
  if (e < 32640) {                       // L vertical
    int h = e >> 7, w = e & 127;
    u = (h << 8) + w; v = u + 256;
  } else if (e < 65152) {                // L horizontal
    int k = e - 32640; int h = k / 127, w = k - h * 127;
    u = (h << 8) + w; v = u + 1;
  } else if (e < 97792) {                // R vertical
    int k = e - 65152; int h = k >> 7, w = k & 127;
    u = (h << 8) + 128 + w; v = u + 256;
  } else if (e < 130304) {               // R horizontal
    int k = e - 97792; int h = k / 127, w = k - h * 127;
    u = (h << 8) + 128 + w; v = u + 1;
  } else {                               // cross
    int k = e - 130304; int h = k >> 7, w = k & 127;
    u = (h << 8) + w; v = u + 128;
  }
}

// Chase to effective root: self-loop, or min-id member of a 2-cycle
// (== reference cyc-break). Verified exact R1-R13. Requires stable parent.
__device__ __forceinline__ int find_root(const int* __restrict__ par, int v) {
  int cur = v;
  int p = par[cur];
  for (int g = 0; g < 70000 && p != cur; ++g) {
    int gp = par[p];
    if (gp == cur) { cur = cur < p ? cur : p; break; }   // 2-cycle -> min id
    cur = p; p = gp;
  }
  return cur;
}

// Fused head, float4: thread owns pixels (h, w0..w0+3), w0=4q, q=lane (0..63
// spans the full row -> coalesced 16B/lane). L/R split is mid-wave, so the
// c-loop is SINGLE-BODY with clamped dummy loads (no divergence); only the
// emit tail predicates. Per-edge fp64 chains: ascending c, one fma per edge
// per c -> bit-identical to the R13-verified keys.
__global__ void k_weight4(const float* __restrict__ x, ull* __restrict__ wkey,
                          float* __restrict__ out) {
  int idx = blockIdx.x * blockDim.x + threadIdx.x;   // exact B*16384 grid
  int b = idx >> 14, rem = idx & 16383;
  int h = rem >> 6, q = rem & 63;
  int w0 = q << 2;
  bool isL   = q < 32;
  bool hasV  = h < 255;
  bool hasR3 = isL ? (q < 31) : (q < 63);            // edge (w0+3,w0+4) exists
  int voff = hasV ? 256 : 0;                         // dummy when absent
  int roff = hasR3 ? 4 : 0;                          // dummy when absent
  int xoff = isL ? 128 : 0;                          // dummy for right lanes

  const float* xb = x + (long long)b * CHW + (h << 8) + w0;
  double n0 = 0, n1 = 0, n2 = 0, n3 = 0;
  double nd0 = 0, nd1 = 0, nd2 = 0, nd3 = 0, nrt = 0;
  double nc0 = 0, nc1 = 0, nc2 = 0, nc3 = 0;
  double dv0 = 0, dv1 = 0, dv2 = 0, dv3 = 0;
  double dh0 = 0, dh1 = 0, dh2 = 0, dh3 = 0;
  double dx0 = 0, dx1 = 0, dx2 = 0, dx3 = 0;
#pragma unroll 4
  for (int c = 0; c < C; ++c) {
    const float* pc = xb + (long long)c * V;
    float4 a  = *(const float4*)pc;
    float4 dn = *(const float4*)(pc + voff);
    float  rt = pc[roff];
    float4 cr = *(const float4*)(pc + xoff);
    double a0 = a.x, a1 = a.y, a2 = a.z, a3 = a.w;
    double d0 = dn.x, d1 = dn.y, d2 = dn.z, d3 = dn.w;
    double r0 = rt;
    double c0 = cr.x, c1 = cr.y, c2 = cr.z, c3 = cr.w;
    n0 = fma(a0, a0, n0); n1 = fma(a1, a1, n1);
    n2 = fma(a2, a2, n2); n3 = fma(a3, a3, n3);
    nd0 = fma(d0, d0, nd0); nd1 = fma(d1, d1, nd1);
    nd2 = fma(d2, d2, nd2); nd3 = fma(d3, d3, nd3);
    nrt = fma(r0, r0, nrt);
    nc0 = fma(c0, c0, nc0); nc1 = fma(c1, c1, nc1);
    nc2 = fma(c2, c2, nc2); nc3 = fma(c3, c3, nc3);
    dv0 = fma(a0, d0, dv0); dv1 = fma(a1, d1, dv1);
    dv2 = fma(a2, d2, dv2); dv3 = fma(a3, d3, dv3);
    dh0 = fma(a0, a1, dh0); dh1 = fma(a1, a2, dh1);
    dh2 = fma(a2, a3, dh2); dh3 = fma(a3, r0, dh3);
    dx0 = fma(a0, c0, dx0); dx1 = fma(a1, c1, dx1);
    dx2 = fma(a2, c2, dx2); dx3 = fma(a3, c3, dx3);
  }

  ull* wk = wkey + (size_t)b * E;
  float* ob = out + (size_t)b * E;
  auto emit = [&](int e, double nu, double nv, double dot) {
    double denom = fmax(sqrt(nu) * sqrt(nv), 1e-8);
    float wv = (float)(dot / denom);
    unsigned int bits = __float_as_uint(wv);
    if (wv == 0.0f) bits = 0u;                       // collapse -0.0
    unsigned int mapped = bits ^ (((int)bits < 0) ? 0xFFFFFFFFu : 0x80000000u);
    wk[e] = ((ull)mapped << 32) | (unsigned int)e;
    ob[e] = 0.0f;
  };
  int wl0 = isL ? w0 : (w0 - 128);
  int vb = isL ? 0 : 65152, hb = isL ? 32640 : 97792;
  if (hasV) {
    emit(vb + (h << 7) + wl0,     n0, nd0, dv0);
    emit(vb + (h << 7) + wl0 + 1, n1, nd1, dv1);
    emit(vb + (h << 7) + wl0 + 2, n2, nd2, dv2);
    emit(vb + (h << 7) + wl0 + 3, n3, nd3, dv3);
  }
  emit(hb + h * 127 + wl0,     n0, n1, dh0);
  emit(hb + h * 127 + wl0 + 1, n1, n2, dh1);
  emit(hb + h * 127 + wl0 + 2, n2, n3, dh2);
  if (hasR3) emit(hb + h * 127 + wl0 + 3, n3, nrt, dh3);
  if (isL) {
    emit(130304 + (h << 7) + w0,     n0, nc0, dx0);
    emit(130304 + (h << 7) + w0 + 1, n1, nc1, dx1);
    emit(130304 + (h << 7) + w0 + 2, n2, nc2, dx2);
    emit(130304 + (h << 7) + w0 + 3, n3, nc3, dx3);
  }
}

// Round 0 fused: local min over <=5 incident keys; mark + hook + arm BOTH
// minE buffers + flags init. (R13-verified.)
__global__ void k_r0(const ull* __restrict__ wkey, ull* __restrict__ minE0,
                     ull* __restrict__ minE1, int* __restrict__ parent,
                     float* __restrict__ out, int* __restrict__ flags) {
  int idx = blockIdx.x * blockDim.x + threadIdx.x;   // exact B*V grid
  int b = idx >> 16, v = idx & (V - 1);
  int h = v >> 8, w = v & 255;
  bool isL = w < 128;
  int wl = isL ? w : w - 128;
  int vb = isL ? 0 : 65152, hb = isL ? 32640 : 97792;
  const ull* wk = wkey + (size_t)b * E;
  ull m = ~0ULL;
  if (h > 0)    m = min(m, wk[vb + ((h - 1) << 7) + wl]);  // up
  if (h < 255)  m = min(m, wk[vb + (h << 7) + wl]);        // down
  if (wl > 0)   m = min(m, wk[hb + h * 127 + wl - 1]);     // left
  if (wl < 127) m = min(m, wk[hb + h * 127 + wl]);         // right
  m = min(m, wk[130304 + (h << 7) + wl]);                  // cross (both sides)
  int e = (int)(m & 0xFFFFFFFFu);
  int eu, ev; edge_uv(e, eu, ev);
  out[(size_t)b * E + e] = 1.0f;                     // winner (idempotent dup)
  parent[idx] = (v == eu) ? ev : eu;                 // hook to other endpoint
  minE0[idx] = ~0ULL;                                // arm buffer 0
  minE1[idx] = ~0ULL;                                // arm buffer 1
  if (idx < 32) flags[idx] = (idx <= 2) ? 1 : 0;
}

// Per-vertex root snapshot (coalesced first hop). Rounds 1 and 2.
__global__ void k_root(const int* __restrict__ parent, int* __restrict__ root) {
  int idx = blockIdx.x * blockDim.x + threadIdx.x;   // exact B*V grid
  int b = idx >> 16;
  root[idx] = find_root(parent + (b << 16), idx & (V - 1));
}

// Round 1 vmin. (R13-verified.)
__global__ void k_vminR1(const int* __restrict__ root, const ull* __restrict__ wkey,
                         ull* __restrict__ minE) {
  int idx = blockIdx.x * blockDim.x + threadIdx.x;   // exact B*V grid
  int b = idx >> 16, v = idx & (V - 1);
  int h = v >> 8, w = v & 255;
  bool isL = w < 128;
  int wl = isL ? w : w - 128;
  int vb = isL ? 0 : 65152, hb = isL ? 32640 : 97792;
  const int* rt = root + (b << 16);
  const ull* wk = wkey + (size_t)b * E;
  int rme = rt[v];
  ull m = ~0ULL;
  if (h > 0    && rt[v - 256] != rme) m = min(m, wk[vb + ((h - 1) << 7) + wl]);
  if (h < 255  && rt[v + 256] != rme) m = min(m, wk[vb + (h << 7) + wl]);
  if (wl > 0   && rt[v - 1]   != rme) m = min(m, wk[hb + h * 127 + wl - 1]);
  if (wl < 127 && rt[v + 1]   != rme) m = min(m, wk[hb + h * 127 + wl]);
  int xn = isL ? v + 128 : v - 128;
  if (rt[xn] != rme) m = min(m, wk[130304 + (h << 7) + wl]);
  if (m != ~0ULL) atomicMin(minE + (b << 16) + rme, m);  // fire-and-forget
}

// Round 2 vmin + owned-edge append (seeds round-3 frontier). (R13-verified.)
__global__ void k_vminR2(const int* __restrict__ root, const ull* __restrict__ wkey,
                         ull* __restrict__ minE,
                         int* __restrict__ elseg, int* __restrict__ cntblk) {
  __shared__ int lcnt;
  if (threadIdx.x == 0) lcnt = 0;
  __syncthreads();
  int idx = blockIdx.x * blockDim.x + threadIdx.x;   // exact B*V grid
  int b = idx >> 16, v = idx & (V - 1);
  int h = v >> 8, w = v & 255;
  bool isL = w < 128;
  int wl = isL ? w : w - 128;
  int vb = isL ? 0 : 65152, hb = isL ? 32640 : 97792;
  const int* rt = root + (b << 16);
  const ull* wk = wkey + (size_t)b * E;
  int rme = rt[v];
  ull m = ~0ULL;
  int base = blockIdx.x * SEG;
  if (h > 0   && rt[v - 256] != rme) m = min(m, wk[vb + ((h - 1) << 7) + wl]);
  if (wl > 0  && rt[v - 1]   != rme) m = min(m, wk[hb + h * 127 + wl - 1]);
  if (!isL    && rt[v - 128] != rme) m = min(m, wk[130304 + (h << 7) + wl]);
  if (h < 255 && rt[v + 256] != rme) {
    int e = vb + (h << 7) + wl;
    m = min(m, wk[e]);
    elseg[base + atomicAdd(&lcnt, 1)] = e;
  }
  if (wl < 127 && rt[v + 1] != rme) {
    int e = hb + h * 127 + wl;
    m = min(m, wk[e]);
    elseg[base + atomicAdd(&lcnt, 1)] = e;
  }
  if (isL && rt[v + 128] != rme) {
    int e = 130304 + (h << 7) + wl;
    m = min(m, wk[e]);
    elseg[base + atomicAdd(&lcnt, 1)] = e;
  }
  if (m != ~0ULL) atomicMin(minE + (b << 16) + rme, m);  // fire-and-forget
  __syncthreads();
  if (threadIdx.x == 0) cntblk[blockIdx.x] = lcnt;
}

// Rounds 1-2 hook: winners + hook + FULL compression + re-arm. (R13-verified.)
__global__ void k_hookV(ull* __restrict__ minE, const int* __restrict__ root,
                        int* __restrict__ parent, float* __restrict__ out) {
  int idx = blockIdx.x * blockDim.x + threadIdx.x;   // exact B*V grid
  int b = idx >> 16, v = idx & (V - 1);
  int rr = root[idx];
  int np = rr;                                       // compression (non-roots)
  if (rr == v) {
    ull k = minE[idx];
    if (k != ~0ULL) {
      int e = (int)(k & 0xFFFFFFFFu);
      int eu, ev; edge_uv(e, eu, ev);
      const int* rt = root + (b << 16);
      int ru = rt[eu], rv2 = rt[ev];
      out[(size_t)b * E + e] = 1.0f;                 // winner (idempotent dup)
      np = (v == ru) ? rv2 : ru;                     // hook to other component
      minE[idx] = ~0ULL;                             // re-arm dirtied slot
    }
  }
  int* par = parent + (b << 16);
  if (par[v] != np) par[v] = np;
}

// Rounds 3..8 phase A. (R13-verified.)
__global__ void k_edgeA(const int* __restrict__ parent, const ull* __restrict__ wkey,
                        ull* __restrict__ mcur, int* __restrict__ elseg,
                        unsigned int* __restrict__ prblk, int* __restrict__ cntblk,
                        int* __restrict__ flags, int r) {
  if (__hip_atomic_load(flags + r - 1, __ATOMIC_RELAXED,
                        __HIP_MEMORY_SCOPE_AGENT) == 0)
    return;                                          // converged
  int j = blockIdx.x, t = threadIdx.x;
  int n = cntblk[j];
  if (n == 0) return;                                // uniform per block
  __shared__ int lcnt;
  if (t == 0) lcnt = 0;
  int b = j >> 8;                                    // 256 vertex-blocks/batch
  const int* par = parent + (b << 16);
  const ull* wk = wkey + (size_t)b * E;
  ull* mb = mcur + (b << 16);
  int base = j * SEG;
  int se[3]; unsigned int sp[3]; int ns = 0;
#pragma unroll
  for (int it = 0; it < 3; ++it) {                   // reads BEFORE barrier
    int i = t + (it << 8);
    if (i < n) {
      int e = elseg[base + i];
      int u, v; edge_uv(e, u, v);
      int ru = find_root(par, u);
      int rv = find_root(par, v);
      if (ru != rv) {
        ull k = wk[e];
        atomicMin(mb + ru, k);                       // fire-and-forget
        atomicMin(mb + rv, k);
        se[ns] = e;
        sp[ns] = ((unsigned int)ru << 16) | (unsigned int)rv;
        ++ns;
      }
    }
  }
  __syncthreads();                                   // all reads done
  for (int i2 = 0; i2 < ns; ++i2) {
    int pos = atomicAdd(&lcnt, 1);                   // LDS, block-local
    elseg[base + pos] = se[i2];
    prblk[base + pos] = sp[i2];
  }
  __syncthreads();
  if (t == 0) {
    cntblk[j] = lcnt;
    if (lcnt &&
        __hip_atomic_load(flags + r, __ATOMIC_RELAXED, __HIP_MEMORY_SCOPE_AGENT) == 0)
      __hip_atomic_fetch_or(flags + r, 1, __ATOMIC_RELAXED, __HIP_MEMORY_SCOPE_AGENT);
  }
}

// Rounds 3..8 phase B. (R13-verified.)
__global__ void k_edgeB(const ull* __restrict__ mcur, ull* __restrict__ mnext,
                        const int* __restrict__ elseg,
                        const unsigned int* __restrict__ prblk,
                        const int* __restrict__ cntblk,
                        int* __restrict__ parent, float* __restrict__ out,
                        const int* __restrict__ flags, int r) {
  if (__hip_atomic_load(flags + r, __ATOMIC_RELAXED,
                        __HIP_MEMORY_SCOPE_AGENT) == 0)
    return;                                          // nothing kept this round
  int j = blockIdx.x, t = threadIdx.x;
  int n = cntblk[j];
  if (n == 0) return;
  int b = j >> 8;
  const ull* mbc = mcur + (b << 16);
  ull* mbn = mnext + (b << 16);
  int* par = parent + (b << 16);
  float* ob = out + (size_t)b * E;
  int base = j * SEG;
  for (int i = t; i < n; i += 256) {
    int e = elseg[base + i];
    unsigned int pr = prblk[base + i];
    int ru = (int)(pr >> 16), rv = (int)(pr & 0xFFFFu);
    ull mu = mbc[ru];                                // cross-dispatch: fresh
    ull mv = mbc[rv];
    bool wu = ((int)(mu & 0xFFFFFFFFu) == e);
    bool wv = ((int)(mv & 0xFFFFFFFFu) == e);
    if (wu | wv) ob[e] = 1.0f;                       // component min edge
    if (wu) par[ru] = rv;                            // unique writer per root
    if (wv) par[rv] = ru;                            // mutual -> 2-cycle
    mbn[ru] = ~0ULL;                                 // arm next buffer
    mbn[rv] = ~0ULL;                                 // (idempotent dups)
  }
}

// Rounds 9..16 in ONE dispatch: one 1024-thread block per batch (frontier is
// tiny by r9). R11-VERIFIED persistent pattern: prefix-gather segments ->
// flat list; per round {chase+atomicMin+ballot-compact | winner-claim/hook |
// agent-scope re-arm}. minE0 is the armed buffer at r9 entry (edgeB(r8)
// arms mnext(r8)=minE0). parent writes/reads stay within one CU (coherent);
// minE accesses use agent-scope atomics (L1 bypass, R11-verified).
__global__ __launch_bounds__(1024)
void k_endgame(int* __restrict__ parent, ull* __restrict__ minE,
               const ull* __restrict__ wkey, float* __restrict__ out,
               int* __restrict__ elseg, unsigned int* __restrict__ prblk,
               const int* __restrict__ cntblk) {
  int b = blockIdx.x, t = threadIdx.x;
  const ull* wk = wkey + (size_t)b * E;
  ull* mb = minE + (b << 16);
  int* par = parent + (b << 16);
  float* ob = out + (size_t)b * E;
  int* feb = elseg + (size_t)b * 256 * SEG;          // batch's flat region
  unsigned int* frb = prblk + (size_t)b * 256 * SEG;

  __shared__ int pre[257];
  __shared__ int wofs[16];
  __shared__ int s_wc;

  // gather segments into a flat compacted list IN PLACE (pre[t] <= t*SEG:
  // every write lands strictly below any unread source)
  if (t == 0) pre[0] = 0;
  if (t < 256) pre[t + 1] = cntblk[(b << 8) + t];
  __syncthreads();
  for (int ofs = 1; ofs < 256; ofs <<= 1) {          // inclusive scan
    int cur = 0, add = 0;
    if (t < 256) { cur = pre[t + 1]; if (t + 1 > ofs) add = pre[t + 1 - ofs]; }
    __syncthreads();
    if (t < 256) pre[t + 1] = cur + add;
    __syncthreads();
  }
  if (t < 256) {
    int dst = pre[t], cnt2 = pre[t + 1] - dst, src = t * SEG;
    for (int i = 0; i < cnt2; ++i) feb[dst + i] = feb[src + i];
  }
  __syncthreads();
  int n = pre[256];

  for (int round = 9; round < ROUNDS && n > 0; ++round) {
    if (t == 0) s_wc = 0;
    __syncthreads();
    for (int base = 0; base < n; base += 1024) {
      int i = base + t;
      bool keep = false; int e = 0; unsigned int pr = 0;
      if (i < n) {
        e = feb[i];
        int u, v; edge_uv(e, u, v);
        int ru = find_root(par, u);
        int rv = find_root(par, v);
        if (ru != rv) {
          keep = true;
          pr = ((unsigned int)ru << 16) | (unsigned int)rv;
          ull k = wk[e];
          atomicMin(mb + ru, k);
          atomicMin(mb + rv, k);
        }
      }
      ull msk = __ballot(keep);
      int lane = t & 63, wid = t >> 6;
      if (lane == 0) wofs[wid] = (int)__popcll(msk);
      __syncthreads();
      if (t == 0) {
        int s = s_wc;
#pragma unroll
        for (int k2 = 0; k2 < 16; ++k2) { int c2 = wofs[k2]; wofs[k2] = s; s += c2; }
        s_wc = s;
      }
      __syncthreads();
      if (keep) {
        int pos = wofs[wid] + (int)__popcll(msk & ((1ULL << lane) - 1));
        feb[pos] = e;                                // pos < base+1024 <= next reads
        frb[pos] = pr;
      }
    }
    __syncthreads();
    int kept = s_wc;
    for (int i = t; i < kept; i += 1024) {           // winner-claim + hook
      unsigned int pr = frb[i];
      int ru = (int)(pr >> 16), rv = (int)(pr & 0xFFFFu);
      int e = feb[i];
      ull mu = __hip_atomic_load(mb + ru, __ATOMIC_RELAXED, __HIP_MEMORY_SCOPE_AGENT);
      ull mv = __hip_atomic_load(mb + rv, __ATOMIC_RELAXED, __HIP_MEMORY_SCOPE_AGENT);
      bool wu = ((int)(mu & 0xFFFFFFFFu) == e);
      bool wv = ((int)(mv & 0xFFFFFFFFu) == e);
      if (wu | wv) ob[e] = 1.0f;
      if (wu) par[ru] = rv;
      if (wv) par[rv] = ru;
    }
    __syncthreads();
    for (int i = t; i < kept; i += 1024) {           // re-arm dirtied slots
      unsigned int pr = frb[i];
      __hip_atomic_store(mb + (int)(pr >> 16), ~0ULL, __ATOMIC_RELAXED,
                         __HIP_MEMORY_SCOPE_AGENT);
      __hip_atomic_store(mb + (int)(pr & 0xFFFFu), ~0ULL, __ATOMIC_RELAXED,
                         __HIP_MEMORY_SCOPE_AGENT);
    }
    n = kept;
    __syncthreads();
  }
}

} // namespace

extern "C" void kernel_launch(void* const* d_in, const int* in_sizes, int n_in,
                              void* d_out, int out_size, void* d_ws, size_t ws_size,
                              hipStream_t stream) {
  const float* x = (const float*)d_in[0];
  float* out = (float*)d_out;

  char* ws = (char*)d_ws;
  size_t off = 0;
  auto alloc = [&](size_t bytes) {
    void* p = (void*)(ws + off);
    off += (bytes + 255) & ~(size_t)255;
    return p;
  };
  int* parent = (int*)alloc((size_t)B * V * sizeof(int));                      // 1 MB
  int* root   = (int*)alloc((size_t)B * V * sizeof(int));                      // 1 MB
  ull* minE0  = (ull*)alloc((size_t)B * V * 8);                                // 2 MB
  ull* minE1  = (ull*)alloc((size_t)B * V * 8);                                // 2 MB
  ull* wkey   = (ull*)alloc((size_t)B * E * 8);                                // ~5.2 MB
  int* elseg  = (int*)alloc((size_t)NBLKV * SEG * sizeof(int));                // 3 MB
  unsigned int* prblk = (unsigned int*)alloc((size_t)NBLKV * SEG * 4);         // 3 MB
  int* cntblk = (int*)alloc((size_t)NBLKV * sizeof(int));
  int* flags  = (int*)alloc(32 * sizeof(int));

  k_weight4<<<(B * 16384) / 256, 256, 0, stream>>>(x, wkey, out);
  k_r0     <<<(B * V) / 256, 256, 0, stream>>>(wkey, minE0, minE1, parent, out, flags);

  // round 1 (per-vertex, minE0)
  k_root  <<<NBLKV, 256, 0, stream>>>(parent, root);
  k_vminR1<<<NBLKV, 256, 0, stream>>>(root, wkey, minE0);
  k_hookV <<<NBLKV, 256, 0, stream>>>(minE0, root, parent, out);

  // round 2 (per-vertex, minE0; seeds round-3 edge frontier)
  k_root  <<<NBLKV, 256, 0, stream>>>(parent, root);
  k_vminR2<<<NBLKV, 256, 0, stream>>>(root, wkey, minE0, elseg, cntblk);
  k_hookV <<<NBLKV, 256, 0, stream>>>(minE0, root, parent, out);

  // rounds 3..8 (edge frontier, double-buffered minE)
  for (int r = 3; r <= 8; ++r) {
    ull* mcur  = (r & 1) ? minE0 : minE1;            // r3 -> minE0 (armed)
    ull* mnext = (r & 1) ? minE1 : minE0;
    k_edgeA<<<NBLKV, 256, 0, stream>>>(parent, wkey, mcur, elseg, prblk,
                                       cntblk, flags, r);
    k_edgeB<<<NBLKV, 256, 0, stream>>>(mcur, mnext, elseg, prblk, cntblk,
                                       parent, out, flags, r);
  }

  // rounds 9..16 in one dispatch (minE0 is the armed buffer at r9 entry)
  k_endgame<<<B, 1024, 0, stream>>>(parent, minE0, wkey, out, elseg, prblk, cntblk);
}

// Round 15
// 246.409 us; speedup vs baseline: 9.7460x; 1.0797x over previous
//
#include <hip/hip_runtime.h>
#include <stdint.h>

namespace {

typedef unsigned long long ull;
constexpr int B = 4, C = 128, H = 256, W = 256;
constexpr int V = H * W;              // 65536
constexpr int E = 163072;             // 32640+32512+32640+32512+32768
constexpr long long CHW = (long long)C * V;
constexpr int ROUNDS = 17;
constexpr int NBLKV = (B * V) / 256;  // 1024 vertex blocks
constexpr int SEG = 768;              // <=3 owned edges per vertex * 256

// Edge enumeration matches reference concat order: [L-vert, L-horiz, R-vert, R-horiz, cross]
__device__ __forceinline__ void edge_uv(int e, int& u, int& v) {
  if (e < 32640) {                       // L vertical
    int h = e >> 7, w = e & 127;
    u = (h << 8) + w; v = u + 256;
  } else if (e < 65152) {                // L horizontal
    int k = e - 32640; int h = k / 127, w = k - h * 127;
    u = (h << 8) + w; v = u + 1;
  } else if (e < 97792) {                // R vertical
    int k = e - 65152; int h = k >> 7, w = k & 127;
    u = (h << 8) + 128 + w; v = u + 256;
  } else if (e < 130304) {               // R horizontal
    int k = e - 97792; int h = k / 127, w = k - h * 127;
    u = (h << 8) + 128 + w; v = u + 1;
  } else {                               // cross
    int k = e - 130304; int h = k >> 7, w = k & 127;
    u = (h << 8) + w; v = u + 128;
  }
}

// Chase to effective root: self-loop, or min-id member of a 2-cycle
// (== reference cyc-break). Verified exact R1-R14. Requires stable parent.
__device__ __forceinline__ int find_root(const int* __restrict__ par, int v) {
  int cur = v;
  int p = par[cur];
  for (int g = 0; g < 70000 && p != cur; ++g) {
    int gp = par[p];
    if (gp == cur) { cur = cur < p ? cur : p; break; }   // 2-cycle -> min id
    cur = p; p = gp;
  }
  return cur;
}

// Fused head, PER-PIXEL threads (max occupancy: 1024 blocks -> 16 waves/CU).
// Single-body BRANCH-FREE c-loop with clamped dummy offsets (R4's failure
// was per-c conditionals; this has none). 4 coalesced scalar loads + 7
// independent fp64 fma chains per c. Each norm/dot chain is its own
// ascending-c chain -> bit-identical to the R3/R5/R13-verified keys.
// Each thread owns <=3 edges (down/right-in-half/cross-if-L): every edge
// emitted exactly once; out slots zeroed for owned edges (covers all E).
__global__ void k_weight5(const float* __restrict__ x, ull* __restrict__ wkey,
                          float* __restrict__ out) {
  int idx = blockIdx.x * blockDim.x + threadIdx.x;   // exact B*V grid
  int b = idx >> 16, p = idx & (V - 1);
  int h = p >> 8, w = p & 255;
  bool isL = w < 128;
  int wl = isL ? w : w - 128;
  bool hasD = h < 255;
  bool hasR = wl < 127;                              // horiz edge within half
  int voff = hasD ? 256 : 0;                         // dummy when absent
  int roff = hasR ? 1 : 0;                           // dummy when absent
  int xoff = isL ? 128 : 0;                          // dummy for right half

  const float* xb = x + (long long)b * CHW + p;
  double n0 = 0, ndn = 0, nrt = 0, ncr = 0, dd = 0, dr = 0, dx = 0;
#pragma unroll 4
  for (int c = 0; c < C; ++c) {
    const float* pc = xb + (long long)c * V;
    double a  = (double)pc[0];
    double dn = (double)pc[voff];
    double rt = (double)pc[roff];
    double cr = (double)pc[xoff];
    n0  = fma(a, a, n0);
    ndn = fma(dn, dn, ndn);
    nrt = fma(rt, rt, nrt);
    ncr = fma(cr, cr, ncr);
    dd  = fma(a, dn, dd);
    dr  = fma(a, rt, dr);
    dx  = fma(a, cr, dx);
  }

  ull* wk = wkey + (size_t)b * E;
  float* ob = out + (size_t)b * E;
  auto emit = [&](int e, double nu, double nv, double dot) {
    double denom = fmax(sqrt(nu) * sqrt(nv), 1e-8);
    float wv = (float)(dot / denom);
    unsigned int bits = __float_as_uint(wv);
    if (wv == 0.0f) bits = 0u;                       // collapse -0.0
    unsigned int mapped = bits ^ (((int)bits < 0) ? 0xFFFFFFFFu : 0x80000000u);
    wk[e] = ((ull)mapped << 32) | (unsigned int)e;
    ob[e] = 0.0f;
  };
  int vb = isL ? 0 : 65152, hb = isL ? 32640 : 97792;
  if (hasD) emit(vb + (h << 7) + wl, n0, ndn, dd);
  if (hasR) emit(hb + h * 127 + wl, n0, nrt, dr);
  if (isL)  emit(130304 + (h << 7) + w, n0, ncr, dx);
}

// Round 0 fused: local min over <=5 incident keys; mark + hook + arm BOTH
// minE buffers + flags init. (R14-verified.)
__global__ void k_r0(const ull* __restrict__ wkey, ull* __restrict__ minE0,
                     ull* __restrict__ minE1, int* __restrict__ parent,
                     float* __restrict__ out, int* __restrict__ flags) {
  int idx = blockIdx.x * blockDim.x + threadIdx.x;   // exact B*V grid
  int b = idx >> 16, v = idx & (V - 1);
  int h = v >> 8, w = v & 255;
  bool isL = w < 128;
  int wl = isL ? w : w - 128;
  int vb = isL ? 0 : 65152, hb = isL ? 32640 : 97792;
  const ull* wk = wkey + (size_t)b * E;
  ull m = ~0ULL;
  if (h > 0)    m = min(m, wk[vb + ((h - 1) << 7) + wl]);  // up
  if (h < 255)  m = min(m, wk[vb + (h << 7) + wl]);        // down
  if (wl > 0)   m = min(m, wk[hb + h * 127 + wl - 1]);     // left
  if (wl < 127) m = min(m, wk[hb + h * 127 + wl]);         // right
  m = min(m, wk[130304 + (h << 7) + wl]);                  // cross (both sides)
  int e = (int)(m & 0xFFFFFFFFu);
  int eu, ev; edge_uv(e, eu, ev);
  out[(size_t)b * E + e] = 1.0f;                     // winner (idempotent dup)
  parent[idx] = (v == eu) ? ev : eu;                 // hook to other endpoint
  minE0[idx] = ~0ULL;                                // arm buffer 0
  minE1[idx] = ~0ULL;                                // arm buffer 1
  if (idx < 32) flags[idx] = (idx <= 2) ? 1 : 0;
}

// Per-vertex root snapshot (coalesced first hop). Rounds 1 and 2.
__global__ void k_root(const int* __restrict__ parent, int* __restrict__ root) {
  int idx = blockIdx.x * blockDim.x + threadIdx.x;   // exact B*V grid
  int b = idx >> 16;
  root[idx] = find_root(parent + (b << 16), idx & (V - 1));
}

// Round 1 vmin. (R14-verified.)
__global__ void k_vminR1(const int* __restrict__ root, const ull* __restrict__ wkey,
                         ull* __restrict__ minE) {
  int idx = blockIdx.x * blockDim.x + threadIdx.x;   // exact B*V grid
  int b = idx >> 16, v = idx & (V - 1);
  int h = v >> 8, w = v & 255;
  bool isL = w < 128;
  int wl = isL ? w : w - 128;
  int vb = isL ? 0 : 65152, hb = isL ? 32640 : 97792;
  const int* rt = root + (b << 16);
  const ull* wk = wkey + (size_t)b * E;
  int rme = rt[v];
  ull m = ~0ULL;
  if (h > 0    && rt[v - 256] != rme) m = min(m, wk[vb + ((h - 1) << 7) + wl]);
  if (h < 255  && rt[v + 256] != rme) m = min(m, wk[vb + (h << 7) + wl]);
  if (wl > 0   && rt[v - 1]   != rme) m = min(m, wk[hb + h * 127 + wl - 1]);
  if (wl < 127 && rt[v + 1]   != rme) m = min(m, wk[hb + h * 127 + wl]);
  int xn = isL ? v + 128 : v - 128;
  if (rt[xn] != rme) m = min(m, wk[130304 + (h << 7) + wl]);
  if (m != ~0ULL) atomicMin(minE + (b << 16) + rme, m);  // fire-and-forget
}

// Round 2 vmin + owned-edge append (seeds round-3 frontier). (R14-verified.)
__global__ void k_vminR2(const int* __restrict__ root, const ull* __restrict__ wkey,
                         ull* __restrict__ minE,
                         int* __restrict__ elseg, int* __restrict__ cntblk) {
  __shared__ int lcnt;
  if (threadIdx.x == 0) lcnt = 0;
  __syncthreads();
  int idx = blockIdx.x * blockDim.x + threadIdx.x;   // exact B*V grid
  int b = idx >> 16, v = idx & (V - 1);
  int h = v >> 8, w = v & 255;
  bool isL = w < 128;
  int wl = isL ? w : w - 128;
  int vb = isL ? 0 : 65152, hb = isL ? 32640 : 97792;
  const int* rt = root + (b << 16);
  const ull* wk = wkey + (size_t)b * E;
  int rme = rt[v];
  ull m = ~0ULL;
  int base = blockIdx.x * SEG;
  if (h > 0   && rt[v - 256] != rme) m = min(m, wk[vb + ((h - 1) << 7) + wl]);
  if (wl > 0  && rt[v - 1]   != rme) m = min(m, wk[hb + h * 127 + wl - 1]);
  if (!isL    && rt[v - 128] != rme) m = min(m, wk[130304 + (h << 7) + wl]);
  if (h < 255 && rt[v + 256] != rme) {
    int e = vb + (h << 7) + wl;
    m = min(m, wk[e]);
    elseg[base + atomicAdd(&lcnt, 1)] = e;
  }
  if (wl < 127 && rt[v + 1] != rme) {
    int e = hb + h * 127 + wl;
    m = min(m, wk[e]);
    elseg[base + atomicAdd(&lcnt, 1)] = e;
  }
  if (isL && rt[v + 128] != rme) {
    int e = 130304 + (h << 7) + wl;
    m = min(m, wk[e]);
    elseg[base + atomicAdd(&lcnt, 1)] = e;
  }
  if (m != ~0ULL) atomicMin(minE + (b << 16) + rme, m);  // fire-and-forget
  __syncthreads();
  if (threadIdx.x == 0) cntblk[blockIdx.x] = lcnt;
}

// Rounds 1-2 hook: winners + hook + FULL compression + re-arm. (R14-verified.)
__global__ void k_hookV(ull* __restrict__ minE, const int* __restrict__ root,
                        int* __restrict__ parent, float* __restrict__ out) {
  int idx = blockIdx.x * blockDim.x + threadIdx.x;   // exact B*V grid
  int b = idx >> 16, v = idx & (V - 1);
  int rr = root[idx];
  int np = rr;                                       // compression (non-roots)
  if (rr == v) {
    ull k = minE[idx];
    if (k != ~0ULL) {
      int e = (int)(k & 0xFFFFFFFFu);
      int eu, ev; edge_uv(e, eu, ev);
      const int* rt = root + (b << 16);
      int ru = rt[eu], rv2 = rt[ev];
      out[(size_t)b * E + e] = 1.0f;                 // winner (idempotent dup)
      np = (v == ru) ? rv2 : ru;                     // hook to other component
      minE[idx] = ~0ULL;                             // re-arm dirtied slot
    }
  }
  int* par = parent + (b << 16);
  if (par[v] != np) par[v] = np;
}

// Rounds 3..8 phase A. (R14-verified.)
__global__ void k_edgeA(const int* __restrict__ parent, const ull* __restrict__ wkey,
                        ull* __restrict__ mcur, int* __restrict__ elseg,
                        unsigned int* __restrict__ prblk, int* __restrict__ cntblk,
                        int* __restrict__ flags, int r) {
  if (__hip_atomic_load(flags + r - 1, __ATOMIC_RELAXED,
                        __HIP_MEMORY_SCOPE_AGENT) == 0)
    return;                                          // converged
  int j = blockIdx.x, t = threadIdx.x;
  int n = cntblk[j];
  if (n == 0) return;                                // uniform per block
  __shared__ int lcnt;
  if (t == 0) lcnt = 0;
  int b = j >> 8;                                    // 256 vertex-blocks/batch
  const int* par = parent + (b << 16);
  const ull* wk = wkey + (size_t)b * E;
  ull* mb = mcur + (b << 16);
  int base = j * SEG;
  int se[3]; unsigned int sp[3]; int ns = 0;
#pragma unroll
  for (int it = 0; it < 3; ++it) {                   // reads BEFORE barrier
    int i = t + (it << 8);
    if (i < n) {
      int e = elseg[base + i];
      int u, v; edge_uv(e, u, v);
      int ru = find_root(par, u);
      int rv = find_root(par, v);
      if (ru != rv) {
        ull k = wk[e];
        atomicMin(mb + ru, k);                       // fire-and-forget
        atomicMin(mb + rv, k);
        se[ns] = e;
        sp[ns] = ((unsigned int)ru << 16) | (unsigned int)rv;
        ++ns;
      }
    }
  }
  __syncthreads();                                   // all reads done
  for (int i2 = 0; i2 < ns; ++i2) {
    int pos = atomicAdd(&lcnt, 1);                   // LDS, block-local
    elseg[base + pos] = se[i2];
    prblk[base + pos] = sp[i2];
  }
  __syncthreads();
  if (t == 0) {
    cntblk[j] = lcnt;
    if (lcnt &&
        __hip_atomic_load(flags + r, __ATOMIC_RELAXED, __HIP_MEMORY_SCOPE_AGENT) == 0)
      __hip_atomic_fetch_or(flags + r, 1, __ATOMIC_RELAXED, __HIP_MEMORY_SCOPE_AGENT);
  }
}

// Rounds 3..8 phase B. (R14-verified.)
__global__ void k_edgeB(const ull* __restrict__ mcur, ull* __restrict__ mnext,
                        const int* __restrict__ elseg,
                        const unsigned int* __restrict__ prblk,
                        const int* __restrict__ cntblk,
                        int* __restrict__ parent, float* __restrict__ out,
                        const int* __restrict__ flags, int r) {
  if (__hip_atomic_load(flags + r, __ATOMIC_RELAXED,
                        __HIP_MEMORY_SCOPE_AGENT) == 0)
    return;                                          // nothing kept this round
  int j = blockIdx.x, t = threadIdx.x;
  int n = cntblk[j];
  if (n == 0) return;
  int b = j >> 8;
  const ull* mbc = mcur + (b << 16);
  ull* mbn = mnext + (b << 16);
  int* par = parent + (b << 16);
  float* ob = out + (size_t)b * E;
  int base = j * SEG;
  for (int i = t; i < n; i += 256) {
    int e = elseg[base + i];
    unsigned int pr = prblk[base + i];
    int ru = (int)(pr >> 16), rv = (int)(pr & 0xFFFFu);
    ull mu = mbc[ru];                                // cross-dispatch: fresh
    ull mv = mbc[rv];
    bool wu = ((int)(mu & 0xFFFFFFFFu) == e);
    bool wv = ((int)(mv & 0xFFFFFFFFu) == e);
    if (wu | wv) ob[e] = 1.0f;                       // component min edge
    if (wu) par[ru] = rv;                            // unique writer per root
    if (wv) par[rv] = ru;                            // mutual -> 2-cycle
    mbn[ru] = ~0ULL;                                 // arm next buffer
    mbn[rv] = ~0ULL;                                 // (idempotent dups)
  }
}

// Rounds 9..16 in ONE dispatch: one 1024-thread block per batch. (R14-verified.)
__global__ __launch_bounds__(1024)
void k_endgame(int* __restrict__ parent, ull* __restrict__ minE,
               const ull* __restrict__ wkey, float* __restrict__ out,
               int* __restrict__ elseg, unsigned int* __restrict__ prblk,
               const int* __restrict__ cntblk) {
  int b = blockIdx.x, t = threadIdx.x;
  const ull* wk = wkey + (size_t)b * E;
  ull* mb = minE + (b << 16);
  int* par = parent + (b << 16);
  float* ob = out + (size_t)b * E;
  int* feb = elseg + (size_t)b * 256 * SEG;          // batch's flat region
  unsigned int* frb = prblk + (size_t)b * 256 * SEG;

  __shared__ int pre[257];
  __shared__ int wofs[16];
  __shared__ int s_wc;

  // gather segments into a flat compacted list IN PLACE (pre[t] <= t*SEG)
  if (t == 0) pre[0] = 0;
  if (t < 256) pre[t + 1] = cntblk[(b << 8) + t];
  __syncthreads();
  for (int ofs = 1; ofs < 256; ofs <<= 1) {          // inclusive scan
    int cur = 0, add = 0;
    if (t < 256) { cur = pre[t + 1]; if (t + 1 > ofs) add = pre[t + 1 - ofs]; }
    __syncthreads();
    if (t < 256) pre[t + 1] = cur + add;
    __syncthreads();
  }
  if (t < 256) {
    int dst = pre[t], cnt2 = pre[t + 1] - dst, src = t * SEG;
    for (int i = 0; i < cnt2; ++i) feb[dst + i] = feb[src + i];
  }
  __syncthreads();
  int n = pre[256];

  for (int round = 9; round < ROUNDS && n > 0; ++round) {
    if (t == 0) s_wc = 0;
    __syncthreads();
    for (int base = 0; base < n; base += 1024) {
      int i = base + t;
      bool keep = false; int e = 0; unsigned int pr = 0;
      if (i < n) {
        e = feb[i];
        int u, v; edge_uv(e, u, v);
        int ru = find_root(par, u);
        int rv = find_root(par, v);
        if (ru != rv) {
          keep = true;
          pr = ((unsigned int)ru << 16) | (unsigned int)rv;
          ull k = wk[e];
          atomicMin(mb + ru, k);
          atomicMin(mb + rv, k);
        }
      }
      ull msk = __ballot(keep);
      int lane = t & 63, wid = t >> 6;
      if (lane == 0) wofs[wid] = (int)__popcll(msk);
      __syncthreads();
      if (t == 0) {
        int s = s_wc;
#pragma unroll
        for (int k2 = 0; k2 < 16; ++k2) { int c2 = wofs[k2]; wofs[k2] = s; s += c2; }
        s_wc = s;
      }
      __syncthreads();
      if (keep) {
        int pos = wofs[wid] + (int)__popcll(msk & ((1ULL << lane) - 1));
        feb[pos] = e;                                // pos < base+1024 <= next reads
        frb[pos] = pr;
      }
    }
    __syncthreads();
    int kept = s_wc;
    for (int i = t; i < kept; i += 1024) {           // winner-claim + hook
      unsigned int pr = frb[i];
      int ru = (int)(pr >> 16), rv = (int)(pr & 0xFFFFu);
      int e = feb[i];
      ull mu = __hip_atomic_load(mb + ru, __ATOMIC_RELAXED, __HIP_MEMORY_SCOPE_AGENT);
      ull mv = __hip_atomic_load(mb + rv, __ATOMIC_RELAXED, __HIP_MEMORY_SCOPE_AGENT);
      bool wu = ((int)(mu & 0xFFFFFFFFu) == e);
      bool wv = ((int)(mv & 0xFFFFFFFFu) == e);
      if (wu | wv) ob[e] = 1.0f;
      if (wu) par[ru] = rv;
      if (wv) par[rv] = ru;
    }
    __syncthreads();
    for (int i = t; i < kept; i += 1024) {           // re-arm dirtied slots
      unsigned int pr = frb[i];
      __hip_atomic_store(mb + (int)(pr >> 16), ~0ULL, __ATOMIC_RELAXED,
                         __HIP_MEMORY_SCOPE_AGENT);
      __hip_atomic_store(mb + (int)(pr & 0xFFFFu), ~0ULL, __ATOMIC_RELAXED,
                         __HIP_MEMORY_SCOPE_AGENT);
    }
    n = kept;
    __syncthreads();
  }
}

} // namespace

extern "C" void kernel_launch(void* const* d_in, const int* in_sizes, int n_in,
                              void* d_out, int out_size, void* d_ws, size_t ws_size,
                              hipStream_t stream) {
  const float* x = (const float*)d_in[0];
  float* out = (float*)d_out;

  char* ws = (char*)d_ws;
  size_t off = 0;
  auto alloc = [&](size_t bytes) {
    void* p = (void*)(ws + off);
    off += (bytes + 255) & ~(size_t)255;
    return p;
  };
  int* parent = (int*)alloc((size_t)B * V * sizeof(int));                      // 1 MB
  int* root   = (int*)alloc((size_t)B * V * sizeof(int));                      // 1 MB
  ull* minE0  = (ull*)alloc((size_t)B * V * 8);                                // 2 MB
  ull* minE1  = (ull*)alloc((size_t)B * V * 8);                                // 2 MB
  ull* wkey   = (ull*)alloc((size_t)B * E * 8);                                // ~5.2 MB
  int* elseg  = (int*)alloc((size_t)NBLKV * SEG * sizeof(int));                // 3 MB
  unsigned int* prblk = (unsigned int*)alloc((size_t)NBLKV * SEG * 4);         // 3 MB
  int* cntblk = (int*)alloc((size_t)NBLKV * sizeof(int));
  int* flags  = (int*)alloc(32 * sizeof(int));

  k_weight5<<<(B * V) / 256, 256, 0, stream>>>(x, wkey, out);
  k_r0     <<<(B * V) / 256, 256, 0, stream>>>(wkey, minE0, minE1, parent, out, flags);

  // round 1 (per-vertex, minE0)
  k_root  <<<NBLKV, 256, 0, stream>>>(parent, root);
  k_vminR1<<<NBLKV, 256, 0, stream>>>(root, wkey, minE0);
  k_hookV <<<NBLKV, 256, 0, stream>>>(minE0, root, parent, out);

  // round 2 (per-vertex, minE0; seeds round-3 edge frontier)
  k_root  <<<NBLKV, 256, 0, stream>>>(parent, root);
  k_vminR2<<<NBLKV, 256, 0, stream>>>(root, wkey, minE0, elseg, cntblk);
  k_hookV <<<NBLKV, 256, 0, stream>>>(minE0, root, parent, out);

  // rounds 3..8 (edge frontier, double-buffered minE)
  for (int r = 3; r <= 8; ++r) {
    ull* mcur  = (r & 1) ? minE0 : minE1;            // r3 -> minE0 (armed)
    ull* mnext = (r & 1) ? minE1 : minE0;
    k_edgeA<<<NBLKV, 256, 0, stream>>>(parent, wkey, mcur, elseg, prblk,
                                       cntblk, flags, r);
    k_edgeB<<<NBLKV, 256, 0, stream>>>(mcur, mnext, elseg, prblk, cntblk,
                                       parent, out, flags, r);
  }

  // rounds 9..16 in one dispatch (minE0 is the armed buffer at r9 entry)
  k_endgame<<<B, 1024, 0, stream>>>(parent, minE0, wkey, out, elseg, prblk, cntblk);
}